// Round 1
// baseline (49225.931 us; speedup 1.0000x reference)
//
#include <hip/hip_runtime.h>
#include <math.h>

#define TPB 256

// ---------------- generic conv1d ----------------
// y[n,co,to] = bias[co] + sum_{ci,k} act(x[n,ci,to*stride-pad+k]) * w[co,ci,k]  (+ res[n,co,to])
template<int K, bool RELU>
__global__ __launch_bounds__(TPB) void conv1d_k(
    const float* __restrict__ x, const float* __restrict__ w,
    const float* __restrict__ bias, const float* __restrict__ res,
    float* __restrict__ y,
    int N, int Ci, int T, int Co, int To, int stride, int pad)
{
    int id = blockIdx.x * TPB + threadIdx.x;
    int total = N * Co * To;
    if (id >= total) return;
    int to = id % To;
    int co = (id / To) % Co;
    int n  = id / (To * Co);
    const float* xn = x + (size_t)n * Ci * T;
    const float* wc = w + (size_t)co * Ci * K;
    float acc = bias[co];
    int h0 = to * stride - pad;
    for (int ci = 0; ci < Ci; ++ci) {
        const float* xc = xn + (size_t)ci * T;
        const float* wk = wc + (size_t)ci * K;
        #pragma unroll
        for (int k = 0; k < K; ++k) {
            int pos = h0 + k;
            if (pos >= 0 && pos < T) {
                float v = xc[pos];
                if (RELU) v = fmaxf(v, 0.0f);
                acc = fmaf(v, wk[k], acc);
            }
        }
    }
    if (res) acc += res[id];
    y[id] = acc;
}

// ---------------- ConvTranspose1d, stride=2 pad=1 K=4 ----------------
// torch semantics: y[ti*2 + k - 1] += x[ti] * w[ci,co,k]
// Each thread computes the output PAIR (2p, 2p+1) so every lane uses the same k set
// (uniform weight loads, no parity divergence):
//   even 2p   : x[p]*w1 + x[p-1]*w3
//   odd  2p+1 : x[p+1]*w0 + x[p]*w2
__global__ __launch_bounds__(TPB) void convt1d_k(
    const float* __restrict__ x, const float* __restrict__ w,
    const float* __restrict__ bias, float* __restrict__ y,
    int N, int Ci, int T, int Co)
{
    int id = blockIdx.x * TPB + threadIdx.x;
    int total = N * Co * T;
    if (id >= total) return;
    int p  = id % T;
    int co = (id / T) % Co;
    int n  = id / (T * Co);
    const float* xn = x + (size_t)n * Ci * T;
    float b = bias[co];
    float acc_e = b, acc_o = b;
    bool hasm = (p >= 1), hasp = (p + 1) < T;
    for (int ci = 0; ci < Ci; ++ci) {
        const float* xc = xn + (size_t)ci * T;
        const float* wc = w + ((size_t)ci * Co + co) * 4;
        float x0 = xc[p];
        float xm = hasm ? xc[p - 1] : 0.0f;
        float xp = hasp ? xc[p + 1] : 0.0f;
        acc_e = fmaf(x0, wc[1], acc_e);
        acc_e = fmaf(xm, wc[3], acc_e);
        acc_o = fmaf(xp, wc[0], acc_o);
        acc_o = fmaf(x0, wc[2], acc_o);
    }
    float2* yp = (float2*)(y + ((size_t)n * Co + co) * (size_t)(2 * T) + (size_t)(2 * p));
    *yp = make_float2(acc_e, acc_o);
}

// ---------------- VQ ----------------
#define NVEC 16384   // 16 * 1024 vectors per codebook
#define KC   4096
#define DD   64

__global__ __launch_bounds__(TPB) void vq_norms_k(
    const float* __restrict__ emb1, const float* __restrict__ emb2,
    float* __restrict__ enorm)  // [2][4096]
{
    int id = blockIdx.x * TPB + threadIdx.x;
    if (id >= 2 * KC) return;
    const float* e = (id < KC) ? (emb1 + (size_t)id * DD) : (emb2 + (size_t)(id - KC) * DD);
    float s = 0.f;
    #pragma unroll
    for (int d = 0; d < DD; ++d) s = fmaf(e[d], e[d], s);
    enorm[id] = s;
}

// grid: (NVEC/256, 4 chunks, 2 codebooks). Same expansion as reference:
// score = ||e||^2 - 2 x.e ; true dist = score + ||x||^2 (added at the end).
__global__ __launch_bounds__(TPB) void vq_partial_k(
    const float* __restrict__ z,       // [16,128,1024]
    const float* __restrict__ emb1, const float* __restrict__ emb2,
    const float* __restrict__ enorm,
    float* __restrict__ pmin, int* __restrict__ pidx)  // [2][4][NVEC]
{
    int v     = blockIdx.x * TPB + threadIdx.x;
    int chunk = blockIdx.y;
    int cb    = blockIdx.z;
    const float* emb = cb ? emb2 : emb1;
    const float* en  = enorm + cb * KC;
    int b = v >> 10, t = v & 1023;
    const float* zp = z + ((size_t)b * 128 + cb * 64) * 1024 + t;
    float xv[DD];
    #pragma unroll
    for (int d = 0; d < DD; ++d) xv[d] = zp[(size_t)d * 1024];

    float best = 1e30f; int bi = 0;
    int c0 = chunk * (KC / 4);
    for (int c = c0; c < c0 + KC / 4; c += 4) {
        const float* e = emb + (size_t)c * DD;
        float d0 = 0.f, d1 = 0.f, d2 = 0.f, d3 = 0.f;
        #pragma unroll
        for (int d = 0; d < DD; ++d) {
            float xd = xv[d];
            d0 = fmaf(xd, e[d], d0);
            d1 = fmaf(xd, e[DD + d], d1);
            d2 = fmaf(xd, e[2 * DD + d], d2);
            d3 = fmaf(xd, e[3 * DD + d], d3);
        }
        float s0 = en[c]     - 2.0f * d0;
        float s1 = en[c + 1] - 2.0f * d1;
        float s2 = en[c + 2] - 2.0f * d2;
        float s3 = en[c + 3] - 2.0f * d3;
        if (s0 < best) { best = s0; bi = c; }
        if (s1 < best) { best = s1; bi = c + 1; }
        if (s2 < best) { best = s2; bi = c + 2; }
        if (s3 < best) { best = s3; bi = c + 3; }
    }
    float xn = 0.f;
    #pragma unroll
    for (int d = 0; d < DD; ++d) xn = fmaf(xv[d], xv[d], xn);
    pmin[((size_t)cb * 4 + chunk) * NVEC + v] = best + xn;
    pidx[((size_t)cb * 4 + chunk) * NVEC + v] = bi;
}

__global__ __launch_bounds__(TPB) void vq_finalize_k(
    const float* __restrict__ pmin, const int* __restrict__ pidx,
    int* __restrict__ idxf,   // [2][NVEC]
    float* __restrict__ cnt,  // [2][KC]
    float* __restrict__ csum) // [2]
{
    int gid = blockIdx.x * TPB + threadIdx.x;   // 0 .. 2*NVEC
    int cb  = gid >> 14;
    int v   = gid & (NVEC - 1);
    float best = pmin[((size_t)cb * 4 + 0) * NVEC + v];
    int   bi   = pidx[((size_t)cb * 4 + 0) * NVEC + v];
    #pragma unroll
    for (int ch = 1; ch < 4; ++ch) {
        float m  = pmin[((size_t)cb * 4 + ch) * NVEC + v];
        int   ix = pidx[((size_t)cb * 4 + ch) * NVEC + v];
        if (m < best) { best = m; bi = ix; }
    }
    idxf[cb * NVEC + v] = bi;
    atomicAdd(&cnt[cb * KC + bi], 1.0f);
    // block-reduce min-distance sum (all threads in a block share one cb: NVEC%(TPB)==0)
    float s = best;
    #pragma unroll
    for (int off = 32; off; off >>= 1) s += __shfl_down(s, off, 64);
    __shared__ float wsum[4];
    int wid = threadIdx.x >> 6;
    if ((threadIdx.x & 63) == 0) wsum[wid] = s;
    __syncthreads();
    if (threadIdx.x == 0)
        atomicAdd(&csum[cb], wsum[0] + wsum[1] + wsum[2] + wsum[3]);
}

__global__ __launch_bounds__(TPB) void vq_gather_k(
    const int* __restrict__ idxf,
    const float* __restrict__ emb1, const float* __restrict__ emb2,
    float* __restrict__ q)   // [16,128,1024]
{
    int id = blockIdx.x * TPB + threadIdx.x;  // 16*128*1024
    int t = id & 1023;
    int c = (id >> 10) & 127;
    int b = id >> 17;
    int cb = c >> 6, d = c & 63;
    int v = b * 1024 + t;
    int idx = idxf[cb * NVEC + v];
    const float* emb = cb ? emb2 : emb1;
    q[id] = emb[(size_t)idx * DD + d];
}

__global__ __launch_bounds__(TPB) void vq_stats_k(
    const float* __restrict__ cnt, const float* __restrict__ csum,
    float* __restrict__ out)  // -> d_out + 131072
{
    float h0 = 0.f, h1 = 0.f, u0 = 0.f, u1 = 0.f;
    for (int i = threadIdx.x; i < KC; i += TPB) {
        float a0 = cnt[i]      * (1.0f / NVEC);
        float a1 = cnt[KC + i] * (1.0f / NVEC);
        h0 -= a0 * logf(a0 + 1e-10f);
        h1 -= a1 * logf(a1 + 1e-10f);
        u0 += a0 * logf(a0 * (float)KC + 1e-10f);
        u1 += a1 * logf(a1 * (float)KC + 1e-10f);
    }
    #pragma unroll
    for (int off = 32; off; off >>= 1) {
        h0 += __shfl_down(h0, off, 64);
        h1 += __shfl_down(h1, off, 64);
        u0 += __shfl_down(u0, off, 64);
        u1 += __shfl_down(u1, off, 64);
    }
    __shared__ float red[4][4];
    int wid = threadIdx.x >> 6;
    if ((threadIdx.x & 63) == 0) {
        red[wid][0] = h0; red[wid][1] = h1; red[wid][2] = u0; red[wid][3] = u1;
    }
    __syncthreads();
    if (threadIdx.x == 0) {
        h0 = red[0][0] + red[1][0] + red[2][0] + red[3][0];
        h1 = red[0][1] + red[1][1] + red[2][1] + red[3][1];
        u0 = red[0][2] + red[1][2] + red[2][2] + red[3][2];
        u1 = red[0][3] + red[1][3] + red[2][3] + red[3][3];
        out[0] = 0.25f * (csum[0] + csum[1]) * (1.0f / ((float)NVEC * (float)DD));
        out[1] = u0 + u1;
        out[2] = expf(h0);
        out[3] = expf(h1);
    }
}

// ---------------- host-side helpers ----------------
static void conv(hipStream_t st, const float* xi, const float* w, const float* b,
                 const float* res, float* y, int N, int Ci, int T, int Co, int To,
                 int s, int p, int K, bool relu)
{
    int total = N * Co * To;
    int grid  = (total + TPB - 1) / TPB;
    #define LC(KK, RR) conv1d_k<KK, RR><<<grid, TPB, 0, st>>>(xi, w, b, res, y, N, Ci, T, Co, To, s, p)
    if (relu) {
        if (K == 1) LC(1, true); else if (K == 3) LC(3, true);
        else if (K == 5) LC(5, true); else LC(7, true);
    } else {
        if (K == 1) LC(1, false); else if (K == 3) LC(3, false);
        else if (K == 5) LC(5, false); else LC(7, false);
    }
    #undef LC
}

static void convt(hipStream_t st, const float* xi, const float* w, const float* b,
                  float* y, int N, int Ci, int T, int Co)
{
    int total = N * Co * T;
    convt1d_k<<<(total + TPB - 1) / TPB, TPB, 0, st>>>(xi, w, b, y, N, Ci, T, Co);
}

static void resblocks2(hipStream_t st, float** cur, float** f1, float** f2,
                       const float* w1, const float* b1, const float* w2, const float* b2,
                       int C, int T)
{
    for (int i = 0; i < 2; ++i) {
        conv(st, *cur, w1 + (size_t)i * C * C * 3, b1 + i * C, nullptr, *f1,
             16, C, T, C, T, 1, 1, 3, true);
        conv(st, *f1, w2 + (size_t)i * C * C, b2 + i * C, *cur, *f2,
             16, C, T, C, T, 1, 0, 1, true);
        float* t = *cur; *cur = *f2; *f2 = t;
    }
    // net effect of 2 swaps: result lands back in the caller's original *cur buffer
}

extern "C" void kernel_launch(void* const* d_in, const int* in_sizes, int n_in,
                              void* d_out, int out_size, void* d_ws, size_t ws_size,
                              hipStream_t stream)
{
    const float* x       = (const float*)d_in[0];
    const float* e_c1_w  = (const float*)d_in[1];
    const float* e_c1_b  = (const float*)d_in[2];
    const float* e_r1_w1 = (const float*)d_in[3];
    const float* e_r1_b1 = (const float*)d_in[4];
    const float* e_r1_w2 = (const float*)d_in[5];
    const float* e_r1_b2 = (const float*)d_in[6];
    const float* e_c2_w  = (const float*)d_in[7];
    const float* e_c2_b  = (const float*)d_in[8];
    const float* e_r2_w1 = (const float*)d_in[9];
    const float* e_r2_b1 = (const float*)d_in[10];
    const float* e_r2_w2 = (const float*)d_in[11];
    const float* e_r2_b2 = (const float*)d_in[12];
    const float* e_c3_w  = (const float*)d_in[13];
    const float* e_c3_b  = (const float*)d_in[14];
    const float* e_r3_w1 = (const float*)d_in[15];
    const float* e_r3_b1 = (const float*)d_in[16];
    const float* e_r3_w2 = (const float*)d_in[17];
    const float* e_r3_b2 = (const float*)d_in[18];
    const float* e_pr_w  = (const float*)d_in[19];
    const float* e_pr_b  = (const float*)d_in[20];
    const float* emb1    = (const float*)d_in[21];
    const float* emb2    = (const float*)d_in[22];
    const float* d_pr_w  = (const float*)d_in[23];
    const float* d_pr_b  = (const float*)d_in[24];
    const float* d_r1_w1 = (const float*)d_in[25];
    const float* d_r1_b1 = (const float*)d_in[26];
    const float* d_r1_w2 = (const float*)d_in[27];
    const float* d_r1_b2 = (const float*)d_in[28];
    const float* d_u1_w  = (const float*)d_in[29];
    const float* d_u1_b  = (const float*)d_in[30];
    const float* d_r2_w1 = (const float*)d_in[31];
    const float* d_r2_b1 = (const float*)d_in[32];
    const float* d_r2_w2 = (const float*)d_in[33];
    const float* d_r2_b2 = (const float*)d_in[34];
    const float* d_u2_w  = (const float*)d_in[35];
    const float* d_u2_b  = (const float*)d_in[36];
    const float* d_r3_w1 = (const float*)d_in[37];
    const float* d_r3_b1 = (const float*)d_in[38];
    const float* d_r3_w2 = (const float*)d_in[39];
    const float* d_r3_b2 = (const float*)d_in[40];
    const float* d_u3_w  = (const float*)d_in[41];
    const float* d_u3_b  = (const float*)d_in[42];
    const float* d_outw  = (const float*)d_in[43];
    const float* d_outb  = (const float*)d_in[44];

    // workspace layout: 3 rotating activation buffers (each sized for the max
    // activation 16*128*8192 = 16.78M floats) + VQ scratch  (~203 MB total)
    const size_t BUF = 16777216;
    float* W0   = (float*)d_ws;
    float* W1   = W0 + BUF;
    float* W2   = W1 + BUF;
    float* pmin = W2 + BUF;                 // 2*4*NVEC = 131072
    int*   pidx = (int*)(pmin + 131072);    // 131072
    int*   idxf = pidx + 131072;            // 32768
    float* enorm= (float*)(idxf + 32768);   // 8192
    float* cnt  = enorm + 8192;             // 8192
    float* csum = cnt + 8192;               // 2  (contiguous with cnt for one memset)

    float *A = W0, *B = W1, *C = W2, *t_;
    hipStream_t st = stream;

    // ---------------- encoder ----------------
    conv(st, x, e_c1_w, e_c1_b, nullptr, A, 16, 1, 8192, 128, 4096, 2, 3, 7, false);
    resblocks2(st, &A, &B, &C, e_r1_w1, e_r1_b1, e_r1_w2, e_r1_b2, 128, 4096);
    conv(st, A, e_c2_w, e_c2_b, nullptr, B, 16, 128, 4096, 256, 2048, 2, 2, 5, false);
    t_ = A; A = B; B = t_;
    resblocks2(st, &A, &B, &C, e_r2_w1, e_r2_b1, e_r2_w2, e_r2_b2, 256, 2048);
    conv(st, A, e_c3_w, e_c3_b, nullptr, B, 16, 256, 2048, 384, 1024, 2, 1, 3, false);
    t_ = A; A = B; B = t_;
    resblocks2(st, &A, &B, &C, e_r3_w1, e_r3_b1, e_r3_w2, e_r3_b2, 384, 1024);
    conv(st, A, e_pr_w, e_pr_b, nullptr, B, 16, 384, 1024, 128, 1024, 1, 0, 1, false);
    t_ = A; A = B; B = t_;     // A = z [16,128,1024]

    // ---------------- product VQ ----------------
    hipMemsetAsync(cnt, 0, (8192 + 2) * sizeof(float), st);
    vq_norms_k<<<(2 * KC + TPB - 1) / TPB, TPB, 0, st>>>(emb1, emb2, enorm);
    dim3 pg(NVEC / TPB, 4, 2);
    vq_partial_k<<<pg, TPB, 0, st>>>(A, emb1, emb2, enorm, pmin, pidx);
    vq_finalize_k<<<2 * NVEC / TPB, TPB, 0, st>>>(pmin, pidx, idxf, cnt, csum);
    vq_gather_k<<<16 * 128 * 1024 / TPB, TPB, 0, st>>>(idxf, emb1, emb2, B);
    t_ = A; A = B; B = t_;     // A = q [16,128,1024]

    // ---------------- decoder ----------------
    conv(st, A, d_pr_w, d_pr_b, nullptr, B, 16, 128, 1024, 384, 1024, 1, 0, 1, false);
    t_ = A; A = B; B = t_;
    resblocks2(st, &A, &B, &C, d_r1_w1, d_r1_b1, d_r1_w2, d_r1_b2, 384, 1024);
    convt(st, A, d_u1_w, d_u1_b, B, 16, 384, 1024, 256);
    t_ = A; A = B; B = t_;
    resblocks2(st, &A, &B, &C, d_r2_w1, d_r2_b1, d_r2_w2, d_r2_b2, 256, 2048);
    convt(st, A, d_u2_w, d_u2_b, B, 16, 256, 2048, 128);
    t_ = A; A = B; B = t_;
    resblocks2(st, &A, &B, &C, d_r3_w1, d_r3_b1, d_r3_w2, d_r3_b2, 128, 4096);
    convt(st, A, d_u3_w, d_u3_b, B, 16, 128, 4096, 128);
    t_ = A; A = B; B = t_;     // A = [16,128,8192]
    conv(st, A, d_outw, d_outb, nullptr, (float*)d_out, 16, 128, 8192, 1, 8192, 1, 3, 7, false);

    // ---------------- scalar stats ----------------
    vq_stats_k<<<1, TPB, 0, st>>>(cnt, csum, (float*)d_out + 131072);
}

// Round 3
// 5690.960 us; speedup vs baseline: 8.6498x; 8.6498x over previous
//
#include <hip/hip_runtime.h>
#include <math.h>

#define TPB 256

// ---------------- naive conv1d (kept ONLY for e_c1: Ci=1, tiny) ----------------
template<int K, bool RELU>
__global__ __launch_bounds__(TPB) void conv1d_k(
    const float* __restrict__ x, const float* __restrict__ w,
    const float* __restrict__ bias, const float* __restrict__ res,
    float* __restrict__ y,
    int N, int Ci, int T, int Co, int To, int stride, int pad)
{
    int id = blockIdx.x * TPB + threadIdx.x;
    int total = N * Co * To;
    if (id >= total) return;
    int to = id % To;
    int co = (id / To) % Co;
    int n  = id / (To * Co);
    const float* xn = x + (size_t)n * Ci * T;
    const float* wc = w + (size_t)co * Ci * K;
    float acc = bias[co];
    int h0 = to * stride - pad;
    for (int ci = 0; ci < Ci; ++ci) {
        const float* xc = xn + (size_t)ci * T;
        const float* wk = wc + (size_t)ci * K;
        #pragma unroll
        for (int k = 0; k < K; ++k) {
            int pos = h0 + k;
            if (pos >= 0 && pos < T) {
                float v = xc[pos];
                if (RELU) v = fmaxf(v, 0.0f);
                acc = fmaf(v, wk[k], acc);
            }
        }
    }
    if (res) acc += res[id];
    y[id] = acc;
}

// ---------------- tiled conv1d ----------------
// Block computes 64 co x 128 t outputs for one n. 256 threads, acc[4co][8t]/thread.
// thread map: t_g = tid&15 (t base = t_g*8), co_g = tid>>4 (co base = co_g*4).
// Ci staged in chunks of 16 into LDS; w reordered to [ci][k][co] (row pad 68)
// so compute reads are float4 broadcasts. Summation order matches the naive
// kernel exactly: acc starts at bias, ci ascending, k ascending.
template<int K, int S, bool RELU, bool RES>
__global__ __launch_bounds__(TPB) void conv_tile_k(
    const float* __restrict__ x, const float* __restrict__ w,
    const float* __restrict__ bias, const float* __restrict__ res,
    float* __restrict__ y, int Ci, int Ti, int Co, int To)
{
    constexpr int CC    = 16;
    constexpr int TNEED = 127 * S + K;
    constexpr int RS    = ((TNEED + 3) & ~3) + 4;
    constexpr int NXV   = 7 * S + K;
    constexpr int NV4   = (NXV + 3) / 4;
    constexpr int WROW  = 68;
    __shared__ float xs[CC][RS];
    __shared__ float ws[CC * K * WROW];

    const int tid   = threadIdx.x;
    const int t_g   = tid & 15;
    const int co_g  = tid >> 4;
    const int tg8S  = t_g * 8 * S;
    const int co_g4 = co_g * 4;
    const int n     = blockIdx.z;
    const int co0   = blockIdx.y * 64;
    const int tb    = blockIdx.x * 128;
    const int t0in  = tb * S - K / 2;

    float4 b4 = *(const float4*)&bias[co0 + co_g4];
    float bi[4] = {b4.x, b4.y, b4.z, b4.w};
    float acc[4][8];
    #pragma unroll
    for (int i = 0; i < 4; ++i)
        #pragma unroll
        for (int j = 0; j < 8; ++j) acc[i][j] = bi[i];

    const int nchunk = Ci / CC;
    for (int ch = 0; ch < nchunk; ++ch) {
        const int ci0 = ch * CC;
        __syncthreads();
        // stage x (coalesced rows, zero-pad boundaries, optional ReLU)
        for (int lin = tid; lin < CC * TNEED; lin += TPB) {
            int r = lin / TNEED, off = lin - r * TNEED;
            int t = t0in + off;
            float v = 0.f;
            if (t >= 0 && t < Ti) {
                v = x[((size_t)(n * Ci + ci0 + r)) * Ti + t];
                if (RELU) v = fmaxf(v, 0.f);
            }
            xs[r][off] = v;
        }
        // stage w: global [co][ci][k] (coalesced runs of CC*K) -> LDS [ci][k][co]
        for (int lin = tid; lin < 64 * CC * K; lin += TPB) {
            int co_l = lin / (CC * K), rem = lin - co_l * (CC * K);
            ws[rem * WROW + co_l] =
                w[(size_t)(co0 + co_l) * Ci * K + (size_t)ci0 * K + rem];
        }
        __syncthreads();
        for (int r = 0; r < CC; ++r) {
            float xv[NV4 * 4];
            #pragma unroll
            for (int q = 0; q < NV4; ++q)
                *(float4*)&xv[q * 4] = *(const float4*)&xs[r][tg8S + q * 4];
            #pragma unroll
            for (int k = 0; k < K; ++k) {
                float4 wv = *(const float4*)&ws[(r * K + k) * WROW + co_g4];
                float wa[4] = {wv.x, wv.y, wv.z, wv.w};
                #pragma unroll
                for (int i = 0; i < 4; ++i)
                    #pragma unroll
                    for (int j = 0; j < 8; ++j)
                        acc[i][j] = fmaf(wa[i], xv[j * S + k], acc[i][j]);
            }
        }
    }
    // epilogue
    #pragma unroll
    for (int i = 0; i < 4; ++i) {
        size_t yb = ((size_t)(n * Co + co0 + co_g4 + i)) * To + tb + t_g * 8;
        float4 lo = make_float4(acc[i][0], acc[i][1], acc[i][2], acc[i][3]);
        float4 hi = make_float4(acc[i][4], acc[i][5], acc[i][6], acc[i][7]);
        if (RES) {
            float4 r0 = *(const float4*)&res[yb];
            float4 r1 = *(const float4*)&res[yb + 4];
            lo.x += r0.x; lo.y += r0.y; lo.z += r0.z; lo.w += r0.w;
            hi.x += r1.x; hi.y += r1.y; hi.z += r1.z; hi.w += r1.w;
        }
        *(float4*)&y[yb]     = lo;
        *(float4*)&y[yb + 4] = hi;
    }
}

// ---------------- tiled ConvTranspose1d (K=4, S=2, pad=1) ----------------
// Block: 64 co x 64 input positions p (=128 outputs) for one n.
// even out 2p:  x[p]*w1 + x[p-1]*w3 ; odd 2p+1: x[p+1]*w0 + x[p]*w2
// FMA order per ci matches the previously-passing pair kernel exactly.
__global__ __launch_bounds__(TPB) void convt_tile_k(
    const float* __restrict__ x, const float* __restrict__ w,
    const float* __restrict__ bias, float* __restrict__ y,
    int Ci, int Ti, int Co)
{
    constexpr int CC = 16, PNEED = 66, RSX = 72, WROW = 68;
    __shared__ float xs[CC][RSX];
    __shared__ float ws[CC * 4 * WROW];

    const int tid   = threadIdx.x;
    const int p_g   = tid & 15;
    const int co_g  = tid >> 4;
    const int pg4   = p_g * 4;
    const int co_g4 = co_g * 4;
    const int n     = blockIdx.z;
    const int co0   = blockIdx.y * 64;
    const int p0    = blockIdx.x * 64;

    float4 b4 = *(const float4*)&bias[co0 + co_g4];
    float bi[4] = {b4.x, b4.y, b4.z, b4.w};
    float accE[4][4], accO[4][4];
    #pragma unroll
    for (int i = 0; i < 4; ++i)
        #pragma unroll
        for (int j = 0; j < 4; ++j) { accE[i][j] = bi[i]; accO[i][j] = bi[i]; }

    const int nchunk = Ci / CC;
    for (int ch = 0; ch < nchunk; ++ch) {
        const int ci0 = ch * CC;
        __syncthreads();
        for (int lin = tid; lin < CC * PNEED; lin += TPB) {
            int r = lin / PNEED, off = lin - r * PNEED;
            int t = p0 - 1 + off;
            xs[r][off] = (t >= 0 && t < Ti)
                ? x[((size_t)(n * Ci + ci0 + r)) * Ti + t] : 0.f;
        }
        // w: global [ci][co][k] -> one float4 per (ci,co) covers all 4 k
        #pragma unroll
        for (int it = 0; it < 4; ++it) {
            int f4i = it * TPB + tid;           // 0..1023
            int r = f4i >> 6, co_l = f4i & 63;
            float4 w4 = *(const float4*)&w[((size_t)(ci0 + r) * Co + co0 + co_l) * 4];
            ws[(r * 4 + 0) * WROW + co_l] = w4.x;
            ws[(r * 4 + 1) * WROW + co_l] = w4.y;
            ws[(r * 4 + 2) * WROW + co_l] = w4.z;
            ws[(r * 4 + 3) * WROW + co_l] = w4.w;
        }
        __syncthreads();
        for (int r = 0; r < CC; ++r) {
            float xv[8];
            *(float4*)&xv[0] = *(const float4*)&xs[r][pg4];
            *(float4*)&xv[4] = *(const float4*)&xs[r][pg4 + 4];
            float4 wq0 = *(const float4*)&ws[(r * 4 + 0) * WROW + co_g4];
            float4 wq1 = *(const float4*)&ws[(r * 4 + 1) * WROW + co_g4];
            float4 wq2 = *(const float4*)&ws[(r * 4 + 2) * WROW + co_g4];
            float4 wq3 = *(const float4*)&ws[(r * 4 + 3) * WROW + co_g4];
            float w0[4] = {wq0.x, wq0.y, wq0.z, wq0.w};
            float w1[4] = {wq1.x, wq1.y, wq1.z, wq1.w};
            float w2[4] = {wq2.x, wq2.y, wq2.z, wq2.w};
            float w3[4] = {wq3.x, wq3.y, wq3.z, wq3.w};
            #pragma unroll
            for (int i = 0; i < 4; ++i)
                #pragma unroll
                for (int j = 0; j < 4; ++j) {
                    accE[i][j] = fmaf(xv[j + 1], w1[i], accE[i][j]);
                    accE[i][j] = fmaf(xv[j],     w3[i], accE[i][j]);
                    accO[i][j] = fmaf(xv[j + 2], w0[i], accO[i][j]);
                    accO[i][j] = fmaf(xv[j + 1], w2[i], accO[i][j]);
                }
        }
    }
    #pragma unroll
    for (int i = 0; i < 4; ++i) {
        size_t yb = ((size_t)(n * Co + co0 + co_g4 + i)) * (size_t)(2 * Ti)
                  + (size_t)2 * p0 + pg4 * 2;
        float4 v0 = make_float4(accE[i][0], accO[i][0], accE[i][1], accO[i][1]);
        float4 v1 = make_float4(accE[i][2], accO[i][2], accE[i][3], accO[i][3]);
        *(float4*)&y[yb]     = v0;
        *(float4*)&y[yb + 4] = v1;
    }
}

// ---------------- d_out: Co=1, K=7, pad=3 over Ci=128, T=8192 ----------------
__global__ __launch_bounds__(TPB) void dout_k(
    const float* __restrict__ x, const float* __restrict__ w,
    const float* __restrict__ b, float* __restrict__ y)
{
    __shared__ float xs[520];
    const int n  = blockIdx.y;
    const int tb = blockIdx.x * 512;
    const float b0 = b[0];
    float a0 = b0, a1 = b0;
    const float* xn = x + (size_t)n * 128 * 8192;
    for (int ci = 0; ci < 128; ++ci) {
        __syncthreads();
        for (int off = threadIdx.x; off < 518; off += TPB) {
            int t = tb - 3 + off;
            xs[off] = (t >= 0 && t < 8192) ? xn[(size_t)ci * 8192 + t] : 0.f;
        }
        __syncthreads();
        float xv[8];
        int base = threadIdx.x * 2;
        #pragma unroll
        for (int m = 0; m < 8; ++m) xv[m] = xs[base + m];
        #pragma unroll
        for (int k = 0; k < 7; ++k) {
            float wk = w[ci * 7 + k];
            a0 = fmaf(xv[k],     wk, a0);
            a1 = fmaf(xv[k + 1], wk, a1);
        }
    }
    float2* yp = (float2*)(y + (size_t)n * 8192 + tb + threadIdx.x * 2);
    *yp = make_float2(a0, a1);
}

// ---------------- VQ (unchanged from passing version) ----------------
#define NVEC 16384
#define KC   4096
#define DD   64

__global__ __launch_bounds__(TPB) void vq_norms_k(
    const float* __restrict__ emb1, const float* __restrict__ emb2,
    float* __restrict__ enorm)
{
    int id = blockIdx.x * TPB + threadIdx.x;
    if (id >= 2 * KC) return;
    const float* e = (id < KC) ? (emb1 + (size_t)id * DD) : (emb2 + (size_t)(id - KC) * DD);
    float s = 0.f;
    #pragma unroll
    for (int d = 0; d < DD; ++d) s = fmaf(e[d], e[d], s);
    enorm[id] = s;
}

__global__ __launch_bounds__(TPB) void vq_partial_k(
    const float* __restrict__ z,
    const float* __restrict__ emb1, const float* __restrict__ emb2,
    const float* __restrict__ enorm,
    float* __restrict__ pmin, int* __restrict__ pidx)
{
    int v     = blockIdx.x * TPB + threadIdx.x;
    int chunk = blockIdx.y;
    int cb    = blockIdx.z;
    const float* emb = cb ? emb2 : emb1;
    const float* en  = enorm + cb * KC;
    int b = v >> 10, t = v & 1023;
    const float* zp = z + ((size_t)b * 128 + cb * 64) * 1024 + t;
    float xv[DD];
    #pragma unroll
    for (int d = 0; d < DD; ++d) xv[d] = zp[(size_t)d * 1024];

    float best = 1e30f; int bi = 0;
    int c0 = chunk * (KC / 4);
    for (int c = c0; c < c0 + KC / 4; c += 4) {
        const float* e = emb + (size_t)c * DD;
        float d0 = 0.f, d1 = 0.f, d2 = 0.f, d3 = 0.f;
        #pragma unroll
        for (int d = 0; d < DD; ++d) {
            float xd = xv[d];
            d0 = fmaf(xd, e[d], d0);
            d1 = fmaf(xd, e[DD + d], d1);
            d2 = fmaf(xd, e[2 * DD + d], d2);
            d3 = fmaf(xd, e[3 * DD + d], d3);
        }
        float s0 = en[c]     - 2.0f * d0;
        float s1 = en[c + 1] - 2.0f * d1;
        float s2 = en[c + 2] - 2.0f * d2;
        float s3 = en[c + 3] - 2.0f * d3;
        if (s0 < best) { best = s0; bi = c; }
        if (s1 < best) { best = s1; bi = c + 1; }
        if (s2 < best) { best = s2; bi = c + 2; }
        if (s3 < best) { best = s3; bi = c + 3; }
    }
    float xn = 0.f;
    #pragma unroll
    for (int d = 0; d < DD; ++d) xn = fmaf(xv[d], xv[d], xn);
    pmin[((size_t)cb * 4 + chunk) * NVEC + v] = best + xn;
    pidx[((size_t)cb * 4 + chunk) * NVEC + v] = bi;
}

__global__ __launch_bounds__(TPB) void vq_finalize_k(
    const float* __restrict__ pmin, const int* __restrict__ pidx,
    int* __restrict__ idxf, float* __restrict__ cnt, float* __restrict__ csum)
{
    int gid = blockIdx.x * TPB + threadIdx.x;
    int cb  = gid >> 14;
    int v   = gid & (NVEC - 1);
    float best = pmin[((size_t)cb * 4 + 0) * NVEC + v];
    int   bi   = pidx[((size_t)cb * 4 + 0) * NVEC + v];
    #pragma unroll
    for (int ch = 1; ch < 4; ++ch) {
        float m  = pmin[((size_t)cb * 4 + ch) * NVEC + v];
        int   ix = pidx[((size_t)cb * 4 + ch) * NVEC + v];
        if (m < best) { best = m; bi = ix; }
    }
    idxf[cb * NVEC + v] = bi;
    atomicAdd(&cnt[cb * KC + bi], 1.0f);
    float s = best;
    #pragma unroll
    for (int off = 32; off; off >>= 1) s += __shfl_down(s, off, 64);
    __shared__ float wsum[4];
    int wid = threadIdx.x >> 6;
    if ((threadIdx.x & 63) == 0) wsum[wid] = s;
    __syncthreads();
    if (threadIdx.x == 0)
        atomicAdd(&csum[cb], wsum[0] + wsum[1] + wsum[2] + wsum[3]);
}

__global__ __launch_bounds__(TPB) void vq_gather_k(
    const int* __restrict__ idxf,
    const float* __restrict__ emb1, const float* __restrict__ emb2,
    float* __restrict__ q)
{
    int id = blockIdx.x * TPB + threadIdx.x;
    int t = id & 1023;
    int c = (id >> 10) & 127;
    int b = id >> 17;
    int cb = c >> 6, d = c & 63;
    int v = b * 1024 + t;
    int idx = idxf[cb * NVEC + v];
    const float* emb = cb ? emb2 : emb1;
    q[id] = emb[(size_t)idx * DD + d];
}

__global__ __launch_bounds__(TPB) void vq_stats_k(
    const float* __restrict__ cnt, const float* __restrict__ csum,
    float* __restrict__ out)
{
    float h0 = 0.f, h1 = 0.f, u0 = 0.f, u1 = 0.f;
    for (int i = threadIdx.x; i < KC; i += TPB) {
        float a0 = cnt[i]      * (1.0f / NVEC);
        float a1 = cnt[KC + i] * (1.0f / NVEC);
        h0 -= a0 * logf(a0 + 1e-10f);
        h1 -= a1 * logf(a1 + 1e-10f);
        u0 += a0 * logf(a0 * (float)KC + 1e-10f);
        u1 += a1 * logf(a1 * (float)KC + 1e-10f);
    }
    #pragma unroll
    for (int off = 32; off; off >>= 1) {
        h0 += __shfl_down(h0, off, 64);
        h1 += __shfl_down(h1, off, 64);
        u0 += __shfl_down(u0, off, 64);
        u1 += __shfl_down(u1, off, 64);
    }
    __shared__ float red[4][4];
    int wid = threadIdx.x >> 6;
    if ((threadIdx.x & 63) == 0) {
        red[wid][0] = h0; red[wid][1] = h1; red[wid][2] = u0; red[wid][3] = u1;
    }
    __syncthreads();
    if (threadIdx.x == 0) {
        h0 = red[0][0] + red[1][0] + red[2][0] + red[3][0];
        h1 = red[0][1] + red[1][1] + red[2][1] + red[3][1];
        u0 = red[0][2] + red[1][2] + red[2][2] + red[3][2];
        u1 = red[0][3] + red[1][3] + red[2][3] + red[3][3];
        out[0] = 0.25f * (csum[0] + csum[1]) * (1.0f / ((float)NVEC * (float)DD));
        out[1] = u0 + u1;
        out[2] = expf(h0);
        out[3] = expf(h1);
    }
}

// ---------------- host helpers ----------------
template<int K, int S, bool RELU, bool RES>
static void launch_conv(hipStream_t st, const float* x, const float* w, const float* b,
                        const float* res, float* y, int Ci, int Ti, int Co, int To)
{
    dim3 g(To / 128, Co / 64, 16);
    conv_tile_k<K, S, RELU, RES><<<g, TPB, 0, st>>>(x, w, b, res, y, Ci, Ti, Co, To);
}

static void launch_convt(hipStream_t st, const float* x, const float* w, const float* b,
                         float* y, int Ci, int Ti, int Co)
{
    dim3 g(Ti / 64, Co / 64, 16);
    convt_tile_k<<<g, TPB, 0, st>>>(x, w, b, y, Ci, Ti, Co);
}

static void resblocks_t(hipStream_t st, float** cur, float** f1, float** f2,
                        const float* w1, const float* b1, const float* w2, const float* b2,
                        int C, int T)
{
    for (int i = 0; i < 2; ++i) {
        launch_conv<3, 1, true, false>(st, *cur, w1 + (size_t)i * C * C * 3, b1 + i * C,
                                       nullptr, *f1, C, T, C, T);
        launch_conv<1, 1, true, true>(st, *f1, w2 + (size_t)i * C * C, b2 + i * C,
                                      *cur, *f2, C, T, C, T);
        float* t = *cur; *cur = *f2; *f2 = t;
    }
}

extern "C" void kernel_launch(void* const* d_in, const int* in_sizes, int n_in,
                              void* d_out, int out_size, void* d_ws, size_t ws_size,
                              hipStream_t stream)
{
    const float* x       = (const float*)d_in[0];
    const float* e_c1_w  = (const float*)d_in[1];
    const float* e_c1_b  = (const float*)d_in[2];
    const float* e_r1_w1 = (const float*)d_in[3];
    const float* e_r1_b1 = (const float*)d_in[4];
    const float* e_r1_w2 = (const float*)d_in[5];
    const float* e_r1_b2 = (const float*)d_in[6];
    const float* e_c2_w  = (const float*)d_in[7];
    const float* e_c2_b  = (const float*)d_in[8];
    const float* e_r2_w1 = (const float*)d_in[9];
    const float* e_r2_b1 = (const float*)d_in[10];
    const float* e_r2_w2 = (const float*)d_in[11];
    const float* e_r2_b2 = (const float*)d_in[12];
    const float* e_c3_w  = (const float*)d_in[13];
    const float* e_c3_b  = (const float*)d_in[14];
    const float* e_r3_w1 = (const float*)d_in[15];
    const float* e_r3_b1 = (const float*)d_in[16];
    const float* e_r3_w2 = (const float*)d_in[17];
    const float* e_r3_b2 = (const float*)d_in[18];
    const float* e_pr_w  = (const float*)d_in[19];
    const float* e_pr_b  = (const float*)d_in[20];
    const float* emb1    = (const float*)d_in[21];
    const float* emb2    = (const float*)d_in[22];
    const float* d_pr_w  = (const float*)d_in[23];
    const float* d_pr_b  = (const float*)d_in[24];
    const float* d_r1_w1 = (const float*)d_in[25];
    const float* d_r1_b1 = (const float*)d_in[26];
    const float* d_r1_w2 = (const float*)d_in[27];
    const float* d_r1_b2 = (const float*)d_in[28];
    const float* d_u1_w  = (const float*)d_in[29];
    const float* d_u1_b  = (const float*)d_in[30];
    const float* d_r2_w1 = (const float*)d_in[31];
    const float* d_r2_b1 = (const float*)d_in[32];
    const float* d_r2_w2 = (const float*)d_in[33];
    const float* d_r2_b2 = (const float*)d_in[34];
    const float* d_u2_w  = (const float*)d_in[35];
    const float* d_u2_b  = (const float*)d_in[36];
    const float* d_r3_w1 = (const float*)d_in[37];
    const float* d_r3_b1 = (const float*)d_in[38];
    const float* d_r3_w2 = (const float*)d_in[39];
    const float* d_r3_b2 = (const float*)d_in[40];
    const float* d_u3_w  = (const float*)d_in[41];
    const float* d_u3_b  = (const float*)d_in[42];
    const float* d_outw  = (const float*)d_in[43];
    const float* d_outb  = (const float*)d_in[44];

    const size_t BUF = 16777216;
    float* W0   = (float*)d_ws;
    float* W1   = W0 + BUF;
    float* W2   = W1 + BUF;
    float* pmin = W2 + BUF;
    int*   pidx = (int*)(pmin + 131072);
    int*   idxf = pidx + 131072;
    float* enorm= (float*)(idxf + 32768);
    float* cnt  = enorm + 8192;
    float* csum = cnt + 8192;

    float *A = W0, *B = W1, *C = W2, *t_;
    hipStream_t st = stream;

    // ---------------- encoder ----------------
    {
        int total = 16 * 128 * 4096;
        conv1d_k<7, false><<<(total + TPB - 1) / TPB, TPB, 0, st>>>(
            x, e_c1_w, e_c1_b, nullptr, A, 16, 1, 8192, 128, 4096, 2, 3);
    }
    resblocks_t(st, &A, &B, &C, e_r1_w1, e_r1_b1, e_r1_w2, e_r1_b2, 128, 4096);
    launch_conv<5, 2, false, false>(st, A, e_c2_w, e_c2_b, nullptr, B, 128, 4096, 256, 2048);
    t_ = A; A = B; B = t_;
    resblocks_t(st, &A, &B, &C, e_r2_w1, e_r2_b1, e_r2_w2, e_r2_b2, 256, 2048);
    launch_conv<3, 2, false, false>(st, A, e_c3_w, e_c3_b, nullptr, B, 256, 2048, 384, 1024);
    t_ = A; A = B; B = t_;
    resblocks_t(st, &A, &B, &C, e_r3_w1, e_r3_b1, e_r3_w2, e_r3_b2, 384, 1024);
    launch_conv<1, 1, false, false>(st, A, e_pr_w, e_pr_b, nullptr, B, 384, 1024, 128, 1024);
    t_ = A; A = B; B = t_;     // A = z [16,128,1024]

    // ---------------- product VQ ----------------
    hipMemsetAsync(cnt, 0, (8192 + 2) * sizeof(float), st);
    vq_norms_k<<<(2 * KC + TPB - 1) / TPB, TPB, 0, st>>>(emb1, emb2, enorm);
    dim3 pg(NVEC / TPB, 4, 2);
    vq_partial_k<<<pg, TPB, 0, st>>>(A, emb1, emb2, enorm, pmin, pidx);
    vq_finalize_k<<<2 * NVEC / TPB, TPB, 0, st>>>(pmin, pidx, idxf, cnt, csum);
    vq_gather_k<<<16 * 128 * 1024 / TPB, TPB, 0, st>>>(idxf, emb1, emb2, B);
    t_ = A; A = B; B = t_;     // A = q

    // ---------------- decoder ----------------
    launch_conv<1, 1, false, false>(st, A, d_pr_w, d_pr_b, nullptr, B, 128, 1024, 384, 1024);
    t_ = A; A = B; B = t_;
    resblocks_t(st, &A, &B, &C, d_r1_w1, d_r1_b1, d_r1_w2, d_r1_b2, 384, 1024);
    launch_convt(st, A, d_u1_w, d_u1_b, B, 384, 1024, 256);
    t_ = A; A = B; B = t_;
    resblocks_t(st, &A, &B, &C, d_r2_w1, d_r2_b1, d_r2_w2, d_r2_b2, 256, 2048);
    launch_convt(st, A, d_u2_w, d_u2_b, B, 256, 2048, 128);
    t_ = A; A = B; B = t_;
    resblocks_t(st, &A, &B, &C, d_r3_w1, d_r3_b1, d_r3_w2, d_r3_b2, 128, 4096);
    launch_convt(st, A, d_u3_w, d_u3_b, B, 128, 4096, 128);
    t_ = A; A = B; B = t_;     // A = [16,128,8192]
    {
        dim3 g(16, 16);
        dout_k<<<g, TPB, 0, st>>>(A, d_outw, d_outb, (float*)d_out);
    }

    // ---------------- scalar stats ----------------
    vq_stats_k<<<1, TPB, 0, st>>>(cnt, csum, (float*)d_out + 131072);
}

// Round 4
// 3154.384 us; speedup vs baseline: 15.6056x; 1.8041x over previous
//
#include <hip/hip_runtime.h>
#include <math.h>

#define TPB 256
typedef __bf16 bf16x8 __attribute__((ext_vector_type(8)));
typedef float f32x4 __attribute__((ext_vector_type(4)));

static __device__ __forceinline__ float bf2f(unsigned short h) {
    union { unsigned int u; float f; } x; x.u = ((unsigned int)h) << 16; return x.f;
}
static __device__ __forceinline__ unsigned short f2bf(float f) {
    union { float f; unsigned int u; } x; x.f = f;
    unsigned int r = x.u + 0x7FFFu + ((x.u >> 16) & 1u);
    return (unsigned short)(r >> 16);
}
static __device__ __forceinline__ unsigned int relu_pk(unsigned int v) {
    unsigned int hi = (v & 0x80000000u) ? 0u : (v & 0xFFFF0000u);
    unsigned int lo = (v & 0x8000u) ? 0u : (v & 0xFFFFu);
    return hi | lo;
}
static __device__ __forceinline__ f32x4 MFMA(bf16x8 a, bf16x8 b, f32x4 c) {
    return __builtin_amdgcn_mfma_f32_16x16x32_bf16(a, b, c, 0, 0, 0);
}

// ---------------- naive conv1d (ONLY e_c1: Ci=1) ----------------
template<int K, bool RELU>
__global__ __launch_bounds__(TPB) void conv1d_k(
    const float* __restrict__ x, const float* __restrict__ w,
    const float* __restrict__ bias, const float* __restrict__ res,
    float* __restrict__ y,
    int N, int Ci, int T, int Co, int To, int stride, int pad)
{
    int id = blockIdx.x * TPB + threadIdx.x;
    int total = N * Co * To;
    if (id >= total) return;
    int to = id % To;
    int co = (id / To) % Co;
    int n  = id / (To * Co);
    const float* xn = x + (size_t)n * Ci * T;
    const float* wc = w + (size_t)co * Ci * K;
    float acc = bias[co];
    int h0 = to * stride - pad;
    for (int ci = 0; ci < Ci; ++ci) {
        const float* xc = xn + (size_t)ci * T;
        const float* wk = wc + (size_t)ci * K;
        #pragma unroll
        for (int k = 0; k < K; ++k) {
            int pos = h0 + k;
            if (pos >= 0 && pos < T) {
                float v = xc[pos];
                if (RELU) v = fmaxf(v, 0.0f);
                acc = fmaf(v, wk[k], acc);
            }
        }
    }
    if (res) acc += res[id];
    y[id] = acc;
}

// ---------------- encoder tiled fp32 conv (channel-first) ----------------
// Swapped thread map vs r1: co_g = tid&15, t_g = tid>>4 -> per wave xs reads are
// 4 broadcast addresses (conflict-free) and ws reads 16 consecutive float4 slots
// (2-way, free). Per-output summation order identical to the passing kernel.
template<int K, int S, bool RELU, bool RES>
__global__ __launch_bounds__(TPB) void conv_tile_k(
    const float* __restrict__ x, const float* __restrict__ w,
    const float* __restrict__ bias, const float* __restrict__ res,
    float* __restrict__ y, int Ci, int Ti, int Co, int To)
{
    constexpr int CC    = 16;
    constexpr int TNEED = 127 * S + K;
    constexpr int RS    = ((TNEED + 3) & ~3) + 4;
    constexpr int NXV   = 7 * S + K;
    constexpr int NV4   = (NXV + 3) / 4;
    constexpr int WROW  = 68;
    __shared__ float xs[CC][RS];
    __shared__ float ws[CC * K * WROW];

    const int tid   = threadIdx.x;
    const int co_g  = tid & 15;     // swapped
    const int t_g   = tid >> 4;    // swapped
    const int tg8S  = t_g * 8 * S;
    const int co_g4 = co_g * 4;
    const int n     = blockIdx.z;
    const int co0   = blockIdx.y * 64;
    const int tb    = blockIdx.x * 128;
    const int t0in  = tb * S - K / 2;

    float4 b4 = *(const float4*)&bias[co0 + co_g4];
    float bi[4] = {b4.x, b4.y, b4.z, b4.w};
    float acc[4][8];
    #pragma unroll
    for (int i = 0; i < 4; ++i)
        #pragma unroll
        for (int j = 0; j < 8; ++j) acc[i][j] = bi[i];

    const int nchunk = Ci / CC;
    for (int ch = 0; ch < nchunk; ++ch) {
        const int ci0 = ch * CC;
        __syncthreads();
        for (int lin = tid; lin < CC * TNEED; lin += TPB) {
            int r = lin / TNEED, off = lin - r * TNEED;
            int t = t0in + off;
            float v = 0.f;
            if (t >= 0 && t < Ti) {
                v = x[((size_t)(n * Ci + ci0 + r)) * Ti + t];
                if (RELU) v = fmaxf(v, 0.f);
            }
            xs[r][off] = v;
        }
        for (int lin = tid; lin < 64 * CC * K; lin += TPB) {
            int co_l = lin / (CC * K), rem = lin - co_l * (CC * K);
            ws[rem * WROW + co_l] =
                w[(size_t)(co0 + co_l) * Ci * K + (size_t)ci0 * K + rem];
        }
        __syncthreads();
        for (int r = 0; r < CC; ++r) {
            float xv[NV4 * 4];
            #pragma unroll
            for (int q = 0; q < NV4; ++q)
                *(float4*)&xv[q * 4] = *(const float4*)&xs[r][tg8S + q * 4];
            #pragma unroll
            for (int k = 0; k < K; ++k) {
                float4 wv = *(const float4*)&ws[(r * K + k) * WROW + co_g4];
                float wa[4] = {wv.x, wv.y, wv.z, wv.w};
                #pragma unroll
                for (int i = 0; i < 4; ++i)
                    #pragma unroll
                    for (int j = 0; j < 8; ++j)
                        acc[i][j] = fmaf(wa[i], xv[j * S + k], acc[i][j]);
            }
        }
    }
    #pragma unroll
    for (int i = 0; i < 4; ++i) {
        size_t yb = ((size_t)(n * Co + co0 + co_g4 + i)) * To + tb + t_g * 8;
        float4 lo = make_float4(acc[i][0], acc[i][1], acc[i][2], acc[i][3]);
        float4 hi = make_float4(acc[i][4], acc[i][5], acc[i][6], acc[i][7]);
        if (RES) {
            float4 r0 = *(const float4*)&res[yb];
            float4 r1 = *(const float4*)&res[yb + 4];
            lo.x += r0.x; lo.y += r0.y; lo.z += r0.z; lo.w += r0.w;
            hi.x += r1.x; hi.y += r1.y; hi.z += r1.z; hi.w += r1.w;
        }
        *(float4*)&y[yb]     = lo;
        *(float4*)&y[yb + 4] = hi;
    }
}

// ---------------- decoder: bf16 channel-last MFMA GEMM-conv ----------------
// D[m=t][n=co] = sum_{kk,ci} X[t+TOFF+kk][ci] * Wp[kk][co][ci]
// block: 64t x 64co, 4 waves in 2x2; per wave 2x2 frags of 16x16, K-step=32 ci.
// A-frag: lane m=l&15, k=(l>>4)*8+j (8 contig ci)   -> ds_read_b128 from x_lds[t][ci]
// B-frag: lane n=l&15, k=(l>>4)*8+j                  -> ds_read_b128 from w_lds[co][ci]
// D:      lane n=l&15, m=(l>>4)*4+r                  (m89-verified layout)
template<int K, int TOFF, bool RELU, bool RES, int OSTR, int OOFF>
__global__ __launch_bounds__(TPB) void gconv_k(
    const unsigned short* __restrict__ x, const unsigned short* __restrict__ wp,
    const float* __restrict__ bias, const unsigned short* __restrict__ res,
    unsigned short* __restrict__ y, int Ci, int Tin, int Co, int Tout)
{
    constexpr int XR = 64 + K - 1;
    __shared__ unsigned short x_lds[XR * 40];
    __shared__ unsigned short w_lds[K * 64 * 40];
    const int tid = threadIdx.x;
    const int n = blockIdx.z, co0 = blockIdx.y * 64, P = blockIdx.x * 64;
    const int wid = tid >> 6, l = tid & 63;
    const int wm = wid >> 1, wn = wid & 1;
    const int lr = l & 15, kg = l >> 4;
    f32x4 acc[2][2] = {{{0.f,0.f,0.f,0.f},{0.f,0.f,0.f,0.f}},
                       {{0.f,0.f,0.f,0.f},{0.f,0.f,0.f,0.f}}};
    const int nch = Ci >> 5;
    for (int cc = 0; cc < nch; ++cc) {
        __syncthreads();
        for (int i = tid; i < XR * 4; i += TPB) {
            int r = i >> 2, c4 = i & 3;
            int gr = P + TOFF + r;
            uint4 v = make_uint4(0u, 0u, 0u, 0u);
            if (gr >= 0 && gr < Tin)
                v = *(const uint4*)(x + ((size_t)(n * Tin + gr) * Ci + cc * 32 + c4 * 8));
            if (RELU) { v.x = relu_pk(v.x); v.y = relu_pk(v.y);
                        v.z = relu_pk(v.z); v.w = relu_pk(v.w); }
            *(uint4*)&x_lds[r * 40 + c4 * 8] = v;
        }
        for (int i = tid; i < K * 64 * 4; i += TPB) {
            int r2 = i >> 2, c4 = i & 3;
            *(uint4*)&w_lds[r2 * 40 + c4 * 8] =
                *(const uint4*)(wp + ((size_t)((r2 >> 6) * Co + co0 + (r2 & 63)) * Ci
                                      + cc * 32 + c4 * 8));
        }
        __syncthreads();
        #pragma unroll
        for (int kk = 0; kk < K; ++kk) {
            bf16x8 av0 = *(const bf16x8*)&x_lds[(wm * 32 +      lr + kk) * 40 + kg * 8];
            bf16x8 av1 = *(const bf16x8*)&x_lds[(wm * 32 + 16 + lr + kk) * 40 + kg * 8];
            bf16x8 bv0 = *(const bf16x8*)&w_lds[(kk * 64 + wn * 32 +      lr) * 40 + kg * 8];
            bf16x8 bv1 = *(const bf16x8*)&w_lds[(kk * 64 + wn * 32 + 16 + lr) * 40 + kg * 8];
            acc[0][0] = MFMA(av0, bv0, acc[0][0]);
            acc[0][1] = MFMA(av0, bv1, acc[0][1]);
            acc[1][0] = MFMA(av1, bv0, acc[1][0]);
            acc[1][1] = MFMA(av1, bv1, acc[1][1]);
        }
    }
    float bb[2] = { bias[co0 + wn * 32 + lr], bias[co0 + wn * 32 + 16 + lr] };
    #pragma unroll
    for (int mf = 0; mf < 2; ++mf)
        #pragma unroll
        for (int nf = 0; nf < 2; ++nf) {
            int co = co0 + wn * 32 + nf * 16 + lr;
            #pragma unroll
            for (int r = 0; r < 4; ++r) {
                int m = wm * 32 + mf * 16 + kg * 4 + r;
                int orow = (P + m) * OSTR + OOFF;
                float v = acc[mf][nf][r] + bb[nf];
                size_t oidx = ((size_t)n * Tout + orow) * Co + co;
                if (RES) v += bf2f(res[oidx]);
                y[oidx] = f2bf(v);
            }
        }
}

// weight prep: conv [Co][Ci][K] f32 -> [K][Co][Ci] bf16
__global__ __launch_bounds__(TPB) void prep_conv_k(
    const float* __restrict__ w, unsigned short* __restrict__ out, int Co, int Ci, int K)
{
    int id = blockIdx.x * TPB + threadIdx.x;
    if (id >= K * Co * Ci) return;
    int ci = id % Ci, co = (id / Ci) % Co, k = id / (Ci * Co);
    out[id] = f2bf(w[((size_t)co * Ci + ci) * K + k]);
}
// convT [Ci][Co][4] f32 -> even [2][Co][Ci] (w3,w1), odd [2][Co][Ci] (w2,w0)
__global__ __launch_bounds__(TPB) void prep_convt_k(
    const float* __restrict__ w, unsigned short* __restrict__ oute,
    unsigned short* __restrict__ outo, int Co, int Ci)
{
    int id = blockIdx.x * TPB + threadIdx.x;
    if (id >= 2 * Co * Ci) return;
    int ci = id % Ci, co = (id / Ci) % Co, kp = id / (Ci * Co);
    const float* src = w + ((size_t)ci * Co + co) * 4;
    oute[id] = f2bf(src[3 - 2 * kp]);
    outo[id] = f2bf(src[2 - 2 * kp]);
}

// d_out: Co=1, K=7, channel-last bf16 input [16][8192][128] -> f32 [16][8192]
__global__ __launch_bounds__(TPB) void dout_cl_k(
    const unsigned short* __restrict__ x, const float* __restrict__ w,
    const float* __restrict__ b, float* __restrict__ y)
{
    __shared__ unsigned short xs[262 * 40];
    const int tid = threadIdx.x;
    const int tb = blockIdx.x * 256;
    const int n = blockIdx.y;
    float acc = b[0];
    for (int cc = 0; cc < 4; ++cc) {
        __syncthreads();
        for (int i = tid; i < 262 * 4; i += TPB) {
            int r = i >> 2, c4 = i & 3;
            int gr = tb - 3 + r;
            uint4 v = make_uint4(0u, 0u, 0u, 0u);
            if (gr >= 0 && gr < 8192)
                v = *(const uint4*)(x + ((size_t)(n * 8192 + gr) * 128 + cc * 32 + c4 * 8));
            *(uint4*)&xs[r * 40 + c4 * 8] = v;
        }
        __syncthreads();
        #pragma unroll
        for (int k = 0; k < 7; ++k) {
            const unsigned short* row = &xs[(tid + k) * 40];
            #pragma unroll
            for (int e = 0; e < 32; ++e)
                acc = fmaf(bf2f(row[e]), w[(cc * 32 + e) * 7 + k], acc);
        }
    }
    y[(size_t)n * 8192 + tb + tid] = acc;
}

// ---------------- VQ ----------------
#define NVEC 16384
#define KC   4096
#define DD   64
#define NCH  16

__global__ __launch_bounds__(TPB) void vq_norms_k(
    const float* __restrict__ emb1, const float* __restrict__ emb2,
    float* __restrict__ enorm)
{
    int id = blockIdx.x * TPB + threadIdx.x;
    if (id >= 2 * KC) return;
    const float* e = (id < KC) ? (emb1 + (size_t)id * DD) : (emb2 + (size_t)(id - KC) * DD);
    float s = 0.f;
    #pragma unroll
    for (int d = 0; d < DD; ++d) s = fmaf(e[d], e[d], s);
    enorm[id] = s;
}

// grid (NVEC/256, 16 chunks, 2 cb). Code pointer is wave-uniform -> scalar loads.
__global__ __launch_bounds__(TPB) void vq_partial_k(
    const float* __restrict__ z,
    const float* __restrict__ emb1, const float* __restrict__ emb2,
    const float* __restrict__ enorm,
    float* __restrict__ pmin, int* __restrict__ pidx)
{
    int v  = blockIdx.x * TPB + threadIdx.x;
    int ch = blockIdx.y;
    int cb = blockIdx.z;
    const float* emb = cb ? emb2 : emb1;
    const float* en  = enorm + cb * KC;
    int b = v >> 10, t = v & 1023;
    const float* zp = z + ((size_t)b * 128 + cb * 64) * 1024 + t;
    float xv[DD];
    #pragma unroll
    for (int d = 0; d < DD; ++d) xv[d] = zp[(size_t)d * 1024];

    float best = 1e30f; int bi = 0;
    const int c0 = ch * (KC / NCH);
    for (int c = c0; c < c0 + KC / NCH; ++c) {
        const float* e = emb + (size_t)c * DD;
        float p0 = 0.f, p1 = 0.f, p2 = 0.f, p3 = 0.f;
        #pragma unroll
        for (int d = 0; d < DD; d += 4) {
            p0 = fmaf(xv[d],     e[d],     p0);
            p1 = fmaf(xv[d + 1], e[d + 1], p1);
            p2 = fmaf(xv[d + 2], e[d + 2], p2);
            p3 = fmaf(xv[d + 3], e[d + 3], p3);
        }
        float s = en[c] - 2.0f * ((p0 + p1) + (p2 + p3));
        if (s < best) { best = s; bi = c; }
    }
    float xn = 0.f;
    #pragma unroll
    for (int d = 0; d < DD; ++d) xn = fmaf(xv[d], xv[d], xn);
    pmin[((size_t)cb * NCH + ch) * NVEC + v] = best + xn;
    pidx[((size_t)cb * NCH + ch) * NVEC + v] = bi;
}

__global__ __launch_bounds__(TPB) void vq_finalize_k(
    const float* __restrict__ pmin, const int* __restrict__ pidx,
    int* __restrict__ idxf, float* __restrict__ cnt, float* __restrict__ csum)
{
    int gid = blockIdx.x * TPB + threadIdx.x;
    int cb  = gid >> 14;
    int v   = gid & (NVEC - 1);
    float best = pmin[((size_t)cb * NCH + 0) * NVEC + v];
    int   bi   = pidx[((size_t)cb * NCH + 0) * NVEC + v];
    #pragma unroll
    for (int ch = 1; ch < NCH; ++ch) {
        float m  = pmin[((size_t)cb * NCH + ch) * NVEC + v];
        int   ix = pidx[((size_t)cb * NCH + ch) * NVEC + v];
        if (m < best) { best = m; bi = ix; }
    }
    idxf[cb * NVEC + v] = bi;
    atomicAdd(&cnt[cb * KC + bi], 1.0f);
    float s = best;
    #pragma unroll
    for (int off = 32; off; off >>= 1) s += __shfl_down(s, off, 64);
    __shared__ float wsum[4];
    int wid = threadIdx.x >> 6;
    if ((threadIdx.x & 63) == 0) wsum[wid] = s;
    __syncthreads();
    if (threadIdx.x == 0)
        atomicAdd(&csum[cb], wsum[0] + wsum[1] + wsum[2] + wsum[3]);
}

// q -> channel-last bf16 [16][1024][128]
__global__ __launch_bounds__(TPB) void vq_gather_cl_k(
    const int* __restrict__ idxf,
    const float* __restrict__ emb1, const float* __restrict__ emb2,
    unsigned short* __restrict__ q)
{
    int id = blockIdx.x * TPB + threadIdx.x;    // 16*1024*128
    int c = id & 127;
    int t = (id >> 7) & 1023;
    int n = id >> 17;
    int cb = c >> 6, d = c & 63;
    int idx = idxf[cb * NVEC + n * 1024 + t];
    const float* emb = cb ? emb2 : emb1;
    q[id] = f2bf(emb[(size_t)idx * DD + d]);
}

__global__ __launch_bounds__(TPB) void vq_stats_k(
    const float* __restrict__ cnt, const float* __restrict__ csum,
    float* __restrict__ out)
{
    float h0 = 0.f, h1 = 0.f, u0 = 0.f, u1 = 0.f;
    for (int i = threadIdx.x; i < KC; i += TPB) {
        float a0 = cnt[i]      * (1.0f / NVEC);
        float a1 = cnt[KC + i] * (1.0f / NVEC);
        h0 -= a0 * logf(a0 + 1e-10f);
        h1 -= a1 * logf(a1 + 1e-10f);
        u0 += a0 * logf(a0 * (float)KC + 1e-10f);
        u1 += a1 * logf(a1 * (float)KC + 1e-10f);
    }
    #pragma unroll
    for (int off = 32; off; off >>= 1) {
        h0 += __shfl_down(h0, off, 64);
        h1 += __shfl_down(h1, off, 64);
        u0 += __shfl_down(u0, off, 64);
        u1 += __shfl_down(u1, off, 64);
    }
    __shared__ float red[4][4];
    int wid = threadIdx.x >> 6;
    if ((threadIdx.x & 63) == 0) {
        red[wid][0] = h0; red[wid][1] = h1; red[wid][2] = u0; red[wid][3] = u1;
    }
    __syncthreads();
    if (threadIdx.x == 0) {
        h0 = red[0][0] + red[1][0] + red[2][0] + red[3][0];
        h1 = red[0][1] + red[1][1] + red[2][1] + red[3][1];
        u0 = red[0][2] + red[1][2] + red[2][2] + red[3][2];
        u1 = red[0][3] + red[1][3] + red[2][3] + red[3][3];
        out[0] = 0.25f * (csum[0] + csum[1]) * (1.0f / ((float)NVEC * (float)DD));
        out[1] = u0 + u1;
        out[2] = expf(h0);
        out[3] = expf(h1);
    }
}

// ---------------- host helpers ----------------
template<int K, int S, bool RELU, bool RES>
static void launch_conv(hipStream_t st, const float* x, const float* w, const float* b,
                        const float* res, float* y, int Ci, int Ti, int Co, int To)
{
    dim3 g(To / 128, Co / 64, 16);
    conv_tile_k<K, S, RELU, RES><<<g, TPB, 0, st>>>(x, w, b, res, y, Ci, Ti, Co, To);
}

static void resblocks_t(hipStream_t st, float** cur, float** f1, float** f2,
                        const float* w1, const float* b1, const float* w2, const float* b2,
                        int C, int T)
{
    for (int i = 0; i < 2; ++i) {
        launch_conv<3, 1, true, false>(st, *cur, w1 + (size_t)i * C * C * 3, b1 + i * C,
                                       nullptr, *f1, C, T, C, T);
        launch_conv<1, 1, true, true>(st, *f1, w2 + (size_t)i * C * C, b2 + i * C,
                                      *cur, *f2, C, T, C, T);
        float* t = *cur; *cur = *f2; *f2 = t;
    }
}

template<int K, int TOFF, bool RELU, bool RES, int OSTR, int OOFF>
static void gconv(hipStream_t st, const unsigned short* x, const unsigned short* wp,
                  const float* b, const unsigned short* res, unsigned short* y,
                  int Ci, int Tin, int Co, int Tout)
{
    dim3 g(Tin / 64, Co / 64, 16);
    gconv_k<K, TOFF, RELU, RES, OSTR, OOFF><<<g, TPB, 0, st>>>(x, wp, b, res, y,
                                                               Ci, Tin, Co, Tout);
}

// bf16 decoder resblock pair; result lands back in *cur's buffer
static void dresblock(hipStream_t st, unsigned short* cur, unsigned short* o1,
                      unsigned short* o2, const unsigned short* wpc1,
                      const unsigned short* wpc2, const float* b1, const float* b2,
                      int C, int T)
{
    size_t wc1 = (size_t)3 * C * C, wc2 = (size_t)C * C;
    gconv<3, -1, true, false, 1, 0>(st, cur, wpc1, b1, nullptr, o1, C, T, C, T);
    gconv<1,  0, true, true,  1, 0>(st, o1, wpc2, b2, cur, o2, C, T, C, T);
    gconv<3, -1, true, false, 1, 0>(st, o2, wpc1 + wc1, b1 + C, nullptr, o1, C, T, C, T);
    gconv<1,  0, true, true,  1, 0>(st, o1, wpc2 + wc2, b2 + C, o2, cur, C, T, C, T);
}

static void prep_conv(hipStream_t st, const float* w, unsigned short* out,
                      int Co, int Ci, int K)
{
    int n = K * Co * Ci;
    prep_conv_k<<<(n + TPB - 1) / TPB, TPB, 0, st>>>(w, out, Co, Ci, K);
}
static void prep_convt(hipStream_t st, const float* w, unsigned short* oe,
                       unsigned short* oo, int Co, int Ci)
{
    int n = 2 * Co * Ci;
    prep_convt_k<<<(n + TPB - 1) / TPB, TPB, 0, st>>>(w, oe, oo, Co, Ci);
}

extern "C" void kernel_launch(void* const* d_in, const int* in_sizes, int n_in,
                              void* d_out, int out_size, void* d_ws, size_t ws_size,
                              hipStream_t stream)
{
    const float* x       = (const float*)d_in[0];
    const float* e_c1_w  = (const float*)d_in[1];
    const float* e_c1_b  = (const float*)d_in[2];
    const float* e_r1_w1 = (const float*)d_in[3];
    const float* e_r1_b1 = (const float*)d_in[4];
    const float* e_r1_w2 = (const float*)d_in[5];
    const float* e_r1_b2 = (const float*)d_in[6];
    const float* e_c2_w  = (const float*)d_in[7];
    const float* e_c2_b  = (const float*)d_in[8];
    const float* e_r2_w1 = (const float*)d_in[9];
    const float* e_r2_b1 = (const float*)d_in[10];
    const float* e_r2_w2 = (const float*)d_in[11];
    const float* e_r2_b2 = (const float*)d_in[12];
    const float* e_c3_w  = (const float*)d_in[13];
    const float* e_c3_b  = (const float*)d_in[14];
    const float* e_r3_w1 = (const float*)d_in[15];
    const float* e_r3_b1 = (const float*)d_in[16];
    const float* e_r3_w2 = (const float*)d_in[17];
    const float* e_r3_b2 = (const float*)d_in[18];
    const float* e_pr_w  = (const float*)d_in[19];
    const float* e_pr_b  = (const float*)d_in[20];
    const float* emb1    = (const float*)d_in[21];
    const float* emb2    = (const float*)d_in[22];
    const float* d_pr_w  = (const float*)d_in[23];
    const float* d_pr_b  = (const float*)d_in[24];
    const float* d_r1_w1 = (const float*)d_in[25];
    const float* d_r1_b1 = (const float*)d_in[26];
    const float* d_r1_w2 = (const float*)d_in[27];
    const float* d_r1_b2 = (const float*)d_in[28];
    const float* d_u1_w  = (const float*)d_in[29];
    const float* d_u1_b  = (const float*)d_in[30];
    const float* d_r2_w1 = (const float*)d_in[31];
    const float* d_r2_b1 = (const float*)d_in[32];
    const float* d_r2_w2 = (const float*)d_in[33];
    const float* d_r2_b2 = (const float*)d_in[34];
    const float* d_u2_w  = (const float*)d_in[35];
    const float* d_u2_b  = (const float*)d_in[36];
    const float* d_r3_w1 = (const float*)d_in[37];
    const float* d_r3_b1 = (const float*)d_in[38];
    const float* d_r3_w2 = (const float*)d_in[39];
    const float* d_r3_b2 = (const float*)d_in[40];
    const float* d_u3_w  = (const float*)d_in[41];
    const float* d_u3_b  = (const float*)d_in[42];
    const float* d_outw  = (const float*)d_in[43];
    const float* d_outb  = (const float*)d_in[44];

    // ws layout: 3 fp32 regions (16.78M floats each), VQ scratch, bf16 weights.
    // Decoder bf16 activations alias W0 (two 16.78M-elem halves) and W2.
    const size_t BUF = 16777216;
    float* W0   = (float*)d_ws;
    float* W1   = W0 + BUF;
    float* W2   = W1 + BUF;
    float* pmin = W2 + BUF;                    // 2*16*16384 = 524288
    int*   pidx = (int*)(pmin + 524288);       // 524288
    int*   idxf = pidx + 524288;               // 32768
    float* enorm= (float*)(idxf + 32768);      // 8192
    float* cnt  = enorm + 8192;                // 8192
    float* csum = cnt + 8192;                  // 4 (padded for alignment)
    unsigned short* wp = (unsigned short*)(csum + 4);

    // bf16 weight sub-allocations
    unsigned short* wp_dpr  = wp;                      // 1*384*128
    unsigned short* wp_r1c1 = wp_dpr  + 49152;         // 2*3*384*384
    unsigned short* wp_r1c2 = wp_r1c1 + 884736;        // 2*1*384*384
    unsigned short* wp_u1e  = wp_r1c2 + 294912;        // 2*256*384
    unsigned short* wp_u1o  = wp_u1e  + 196608;
    unsigned short* wp_r2c1 = wp_u1o  + 196608;        // 2*3*256*256
    unsigned short* wp_r2c2 = wp_r2c1 + 393216;        // 2*256*256
    unsigned short* wp_u2e  = wp_r2c2 + 131072;        // 2*128*256
    unsigned short* wp_u2o  = wp_u2e  + 65536;
    unsigned short* wp_r3c1 = wp_u2o  + 65536;         // 2*3*128*128
    unsigned short* wp_r3c2 = wp_r3c1 + 98304;         // 2*128*128
    unsigned short* wp_u3e  = wp_r3c2 + 32768;         // 2*128*128
    unsigned short* wp_u3o  = wp_u3e  + 32768;

    unsigned short* bfA = (unsigned short*)W0;
    unsigned short* bfB = bfA + BUF;       // second half of W0 region
    unsigned short* bfC = (unsigned short*)W2;

    float *A = W0, *B = W1, *C = W2, *t_;
    hipStream_t st = stream;

    // ---------------- decoder weight prep (tiny) ----------------
    prep_conv(st, d_pr_w, wp_dpr, 384, 128, 1);
    prep_conv(st, d_r1_w1,                      wp_r1c1,          384, 384, 3);
    prep_conv(st, d_r1_w1 + (size_t)384*384*3,  wp_r1c1 + 442368, 384, 384, 3);
    prep_conv(st, d_r1_w2,                      wp_r1c2,          384, 384, 1);
    prep_conv(st, d_r1_w2 + (size_t)384*384,    wp_r1c2 + 147456, 384, 384, 1);
    prep_convt(st, d_u1_w, wp_u1e, wp_u1o, 256, 384);
    prep_conv(st, d_r2_w1,                      wp_r2c1,          256, 256, 3);
    prep_conv(st, d_r2_w1 + (size_t)256*256*3,  wp_r2c1 + 196608, 256, 256, 3);
    prep_conv(st, d_r2_w2,                      wp_r2c2,          256, 256, 1);
    prep_conv(st, d_r2_w2 + (size_t)256*256,    wp_r2c2 + 65536,  256, 256, 1);
    prep_convt(st, d_u2_w, wp_u2e, wp_u2o, 128, 256);
    prep_conv(st, d_r3_w1,                      wp_r3c1,          128, 128, 3);
    prep_conv(st, d_r3_w1 + (size_t)128*128*3,  wp_r3c1 + 49152,  128, 128, 3);
    prep_conv(st, d_r3_w2,                      wp_r3c2,          128, 128, 1);
    prep_conv(st, d_r3_w2 + (size_t)128*128,    wp_r3c2 + 16384,  128, 128, 1);
    prep_convt(st, d_u3_w, wp_u3e, wp_u3o, 128, 128);

    // ---------------- encoder (fp32, exact) ----------------
    {
        int total = 16 * 128 * 4096;
        conv1d_k<7, false><<<(total + TPB - 1) / TPB, TPB, 0, st>>>(
            x, e_c1_w, e_c1_b, nullptr, A, 16, 1, 8192, 128, 4096, 2, 3);
    }
    resblocks_t(st, &A, &B, &C, e_r1_w1, e_r1_b1, e_r1_w2, e_r1_b2, 128, 4096);
    launch_conv<5, 2, false, false>(st, A, e_c2_w, e_c2_b, nullptr, B, 128, 4096, 256, 2048);
    t_ = A; A = B; B = t_;
    resblocks_t(st, &A, &B, &C, e_r2_w1, e_r2_b1, e_r2_w2, e_r2_b2, 256, 2048);
    launch_conv<3, 2, false, false>(st, A, e_c3_w, e_c3_b, nullptr, B, 256, 2048, 384, 1024);
    t_ = A; A = B; B = t_;
    resblocks_t(st, &A, &B, &C, e_r3_w1, e_r3_b1, e_r3_w2, e_r3_b2, 384, 1024);
    launch_conv<1, 1, false, false>(st, A, e_pr_w, e_pr_b, nullptr, B, 384, 1024, 128, 1024);
    t_ = A; A = B; B = t_;     // A == W1 == z [16,128,1024]

    // ---------------- product VQ (fp32, exact) ----------------
    hipMemsetAsync(cnt, 0, (8192 + 4) * sizeof(float), st);
    vq_norms_k<<<(2 * KC + TPB - 1) / TPB, TPB, 0, st>>>(emb1, emb2, enorm);
    dim3 pg(NVEC / TPB, NCH, 2);
    vq_partial_k<<<pg, TPB, 0, st>>>(A, emb1, emb2, enorm, pmin, pidx);
    vq_finalize_k<<<2 * NVEC / TPB, TPB, 0, st>>>(pmin, pidx, idxf, cnt, csum);
    vq_gather_cl_k<<<16 * 1024 * 128 / TPB, TPB, 0, st>>>(idxf, emb1, emb2, bfA);

    // ---------------- decoder (bf16 MFMA, channel-last) ----------------
    gconv<1, 0, false, false, 1, 0>(st, bfA, wp_dpr, d_pr_b, nullptr, bfB,
                                    128, 1024, 384, 1024);
    dresblock(st, bfB, bfA, bfC, wp_r1c1, wp_r1c2, d_r1_b1, d_r1_b2, 384, 1024);
    gconv<2, -1, false, false, 2, 0>(st, bfB, wp_u1e, d_u1_b, nullptr, bfA,
                                     384, 1024, 256, 2048);
    gconv<2,  0, false, false, 2, 1>(st, bfB, wp_u1o, d_u1_b, nullptr, bfA,
                                     384, 1024, 256, 2048);
    dresblock(st, bfA, bfB, bfC, wp_r2c1, wp_r2c2, d_r2_b1, d_r2_b2, 256, 2048);
    gconv<2, -1, false, false, 2, 0>(st, bfA, wp_u2e, d_u2_b, nullptr, bfB,
                                     256, 2048, 128, 4096);
    gconv<2,  0, false, false, 2, 1>(st, bfA, wp_u2o, d_u2_b, nullptr, bfB,
                                     256, 2048, 128, 4096);
    dresblock(st, bfB, bfA, bfC, wp_r3c1, wp_r3c2, d_r3_b1, d_r3_b2, 128, 4096);
    gconv<2, -1, false, false, 2, 0>(st, bfB, wp_u3e, d_u3_b, nullptr, bfA,
                                     128, 4096, 128, 8192);
    gconv<2,  0, false, false, 2, 1>(st, bfB, wp_u3o, d_u3_b, nullptr, bfA,
                                     128, 4096, 128, 8192);
    {
        dim3 g(8192 / 256, 16);
        dout_cl_k<<<g, TPB, 0, st>>>(bfA, d_outw, d_outb, (float*)d_out);
    }

    // ---------------- scalar stats ----------------
    vq_stats_k<<<1, TPB, 0, st>>>(cnt, csum, (float*)d_out + 131072);
}

// Round 5
// 3081.906 us; speedup vs baseline: 15.9726x; 1.0235x over previous
//
#include <hip/hip_runtime.h>
#include <math.h>

#define TPB 256
typedef __bf16 bf16x8 __attribute__((ext_vector_type(8)));
typedef float f32x4 __attribute__((ext_vector_type(4)));

static __device__ __forceinline__ float bf2f(unsigned short h) {
    union { unsigned int u; float f; } x; x.u = ((unsigned int)h) << 16; return x.f;
}
static __device__ __forceinline__ unsigned short f2bf(float f) {
    union { float f; unsigned int u; } x; x.f = f;
    unsigned int r = x.u + 0x7FFFu + ((x.u >> 16) & 1u);
    return (unsigned short)(r >> 16);
}
static __device__ __forceinline__ unsigned int relu_pk(unsigned int v) {
    unsigned int hi = (v & 0x80000000u) ? 0u : (v & 0xFFFF0000u);
    unsigned int lo = (v & 0x8000u) ? 0u : (v & 0xFFFFu);
    return hi | lo;
}
static __device__ __forceinline__ f32x4 MFMA(bf16x8 a, bf16x8 b, f32x4 c) {
    return __builtin_amdgcn_mfma_f32_16x16x32_bf16(a, b, c, 0, 0, 0);
}

// ---------------- naive conv1d (ONLY e_c1: Ci=1) ----------------
template<int K, bool RELU>
__global__ __launch_bounds__(TPB) void conv1d_k(
    const float* __restrict__ x, const float* __restrict__ w,
    const float* __restrict__ bias, const float* __restrict__ res,
    float* __restrict__ y,
    int N, int Ci, int T, int Co, int To, int stride, int pad)
{
    int id = blockIdx.x * TPB + threadIdx.x;
    int total = N * Co * To;
    if (id >= total) return;
    int to = id % To;
    int co = (id / To) % Co;
    int n  = id / (To * Co);
    const float* xn = x + (size_t)n * Ci * T;
    const float* wc = w + (size_t)co * Ci * K;
    float acc = bias[co];
    int h0 = to * stride - pad;
    for (int ci = 0; ci < Ci; ++ci) {
        const float* xc = xn + (size_t)ci * T;
        const float* wk = wc + (size_t)ci * K;
        #pragma unroll
        for (int k = 0; k < K; ++k) {
            int pos = h0 + k;
            if (pos >= 0 && pos < T) {
                float v = xc[pos];
                if (RELU) v = fmaxf(v, 0.0f);
                acc = fmaf(v, wk[k], acc);
            }
        }
    }
    if (res) acc += res[id];
    y[id] = acc;
}

// ---------------- encoder tiled fp32 conv (channel-first) ----------------
template<int K, int S, bool RELU, bool RES>
__global__ __launch_bounds__(TPB) void conv_tile_k(
    const float* __restrict__ x, const float* __restrict__ w,
    const float* __restrict__ bias, const float* __restrict__ res,
    float* __restrict__ y, int Ci, int Ti, int Co, int To)
{
    constexpr int CC    = 16;
    constexpr int TNEED = 127 * S + K;
    constexpr int RS    = ((TNEED + 3) & ~3) + 4;
    constexpr int NXV   = 7 * S + K;
    constexpr int NV4   = (NXV + 3) / 4;
    constexpr int WROW  = 68;
    __shared__ float xs[CC][RS];
    __shared__ float ws[CC * K * WROW];

    const int tid   = threadIdx.x;
    const int co_g  = tid & 15;
    const int t_g   = tid >> 4;
    const int tg8S  = t_g * 8 * S;
    const int co_g4 = co_g * 4;
    const int n     = blockIdx.z;
    const int co0   = blockIdx.y * 64;
    const int tb    = blockIdx.x * 128;
    const int t0in  = tb * S - K / 2;

    float4 b4 = *(const float4*)&bias[co0 + co_g4];
    float bi[4] = {b4.x, b4.y, b4.z, b4.w};
    float acc[4][8];
    #pragma unroll
    for (int i = 0; i < 4; ++i)
        #pragma unroll
        for (int j = 0; j < 8; ++j) acc[i][j] = bi[i];

    const int nchunk = Ci / CC;
    for (int ch = 0; ch < nchunk; ++ch) {
        const int ci0 = ch * CC;
        __syncthreads();
        for (int lin = tid; lin < CC * TNEED; lin += TPB) {
            int r = lin / TNEED, off = lin - r * TNEED;
            int t = t0in + off;
            float v = 0.f;
            if (t >= 0 && t < Ti) {
                v = x[((size_t)(n * Ci + ci0 + r)) * Ti + t];
                if (RELU) v = fmaxf(v, 0.f);
            }
            xs[r][off] = v;
        }
        for (int lin = tid; lin < 64 * CC * K; lin += TPB) {
            int co_l = lin / (CC * K), rem = lin - co_l * (CC * K);
            ws[rem * WROW + co_l] =
                w[(size_t)(co0 + co_l) * Ci * K + (size_t)ci0 * K + rem];
        }
        __syncthreads();
        for (int r = 0; r < CC; ++r) {
            float xv[NV4 * 4];
            #pragma unroll
            for (int q = 0; q < NV4; ++q)
                *(float4*)&xv[q * 4] = *(const float4*)&xs[r][tg8S + q * 4];
            #pragma unroll
            for (int k = 0; k < K; ++k) {
                float4 wv = *(const float4*)&ws[(r * K + k) * WROW + co_g4];
                float wa[4] = {wv.x, wv.y, wv.z, wv.w};
                #pragma unroll
                for (int i = 0; i < 4; ++i)
                    #pragma unroll
                    for (int j = 0; j < 8; ++j)
                        acc[i][j] = fmaf(wa[i], xv[j * S + k], acc[i][j]);
            }
        }
    }
    #pragma unroll
    for (int i = 0; i < 4; ++i) {
        size_t yb = ((size_t)(n * Co + co0 + co_g4 + i)) * To + tb + t_g * 8;
        float4 lo = make_float4(acc[i][0], acc[i][1], acc[i][2], acc[i][3]);
        float4 hi = make_float4(acc[i][4], acc[i][5], acc[i][6], acc[i][7]);
        if (RES) {
            float4 r0 = *(const float4*)&res[yb];
            float4 r1 = *(const float4*)&res[yb + 4];
            lo.x += r0.x; lo.y += r0.y; lo.z += r0.z; lo.w += r0.w;
            hi.x += r1.x; hi.y += r1.y; hi.z += r1.z; hi.w += r1.w;
        }
        *(float4*)&y[yb]     = lo;
        *(float4*)&y[yb + 4] = hi;
    }
}

// ---------------- decoder: bf16 channel-last MFMA GEMM-conv ----------------
template<int K, int TOFF, bool RELU, bool RES, int OSTR, int OOFF>
__global__ __launch_bounds__(TPB) void gconv_k(
    const unsigned short* __restrict__ x, const unsigned short* __restrict__ wp,
    const float* __restrict__ bias, const unsigned short* __restrict__ res,
    unsigned short* __restrict__ y, int Ci, int Tin, int Co, int Tout)
{
    constexpr int XR = 64 + K - 1;
    __shared__ unsigned short x_lds[XR * 40];
    __shared__ unsigned short w_lds[K * 64 * 40];
    const int tid = threadIdx.x;
    const int n = blockIdx.z, co0 = blockIdx.y * 64, P = blockIdx.x * 64;
    const int wid = tid >> 6, l = tid & 63;
    const int wm = wid >> 1, wn = wid & 1;
    const int lr = l & 15, kg = l >> 4;
    f32x4 acc[2][2] = {{{0.f,0.f,0.f,0.f},{0.f,0.f,0.f,0.f}},
                       {{0.f,0.f,0.f,0.f},{0.f,0.f,0.f,0.f}}};
    const int nch = Ci >> 5;
    for (int cc = 0; cc < nch; ++cc) {
        __syncthreads();
        for (int i = tid; i < XR * 4; i += TPB) {
            int r = i >> 2, c4 = i & 3;
            int gr = P + TOFF + r;
            uint4 v = make_uint4(0u, 0u, 0u, 0u);
            if (gr >= 0 && gr < Tin)
                v = *(const uint4*)(x + ((size_t)(n * Tin + gr) * Ci + cc * 32 + c4 * 8));
            if (RELU) { v.x = relu_pk(v.x); v.y = relu_pk(v.y);
                        v.z = relu_pk(v.z); v.w = relu_pk(v.w); }
            *(uint4*)&x_lds[r * 40 + c4 * 8] = v;
        }
        for (int i = tid; i < K * 64 * 4; i += TPB) {
            int r2 = i >> 2, c4 = i & 3;
            *(uint4*)&w_lds[r2 * 40 + c4 * 8] =
                *(const uint4*)(wp + ((size_t)((r2 >> 6) * Co + co0 + (r2 & 63)) * Ci
                                      + cc * 32 + c4 * 8));
        }
        __syncthreads();
        #pragma unroll
        for (int kk = 0; kk < K; ++kk) {
            bf16x8 av0 = *(const bf16x8*)&x_lds[(wm * 32 +      lr + kk) * 40 + kg * 8];
            bf16x8 av1 = *(const bf16x8*)&x_lds[(wm * 32 + 16 + lr + kk) * 40 + kg * 8];
            bf16x8 bv0 = *(const bf16x8*)&w_lds[(kk * 64 + wn * 32 +      lr) * 40 + kg * 8];
            bf16x8 bv1 = *(const bf16x8*)&w_lds[(kk * 64 + wn * 32 + 16 + lr) * 40 + kg * 8];
            acc[0][0] = MFMA(av0, bv0, acc[0][0]);
            acc[0][1] = MFMA(av0, bv1, acc[0][1]);
            acc[1][0] = MFMA(av1, bv0, acc[1][0]);
            acc[1][1] = MFMA(av1, bv1, acc[1][1]);
        }
    }
    float bb[2] = { bias[co0 + wn * 32 + lr], bias[co0 + wn * 32 + 16 + lr] };
    #pragma unroll
    for (int mf = 0; mf < 2; ++mf)
        #pragma unroll
        for (int nf = 0; nf < 2; ++nf) {
            int co = co0 + wn * 32 + nf * 16 + lr;
            #pragma unroll
            for (int r = 0; r < 4; ++r) {
                int m = wm * 32 + mf * 16 + kg * 4 + r;
                int orow = (P + m) * OSTR + OOFF;
                float v = acc[mf][nf][r] + bb[nf];
                size_t oidx = ((size_t)n * Tout + orow) * Co + co;
                if (RES) v += bf2f(res[oidx]);
                y[oidx] = f2bf(v);
            }
        }
}

// ---------------- merged ConvTranspose1d (both parities, one staging) ----------
// even out 2p  = sum_kk X[p-1+kk] . We[kk]   (lds row m+kk,   We: [w3,w1])
// odd  out 2p+1= sum_kk X[p+kk]   . Wo[kk]   (lds row m+kk+1, Wo: [w2,w0])
__global__ __launch_bounds__(TPB) void gconvt_k(
    const unsigned short* __restrict__ x, const unsigned short* __restrict__ wpe,
    const unsigned short* __restrict__ wpo, const float* __restrict__ bias,
    unsigned short* __restrict__ y, int Ci, int Tin, int Co)
{
    __shared__ unsigned short x_lds[66 * 40];
    __shared__ unsigned short we_lds[2 * 64 * 40];
    __shared__ unsigned short wo_lds[2 * 64 * 40];
    const int tid = threadIdx.x;
    const int n = blockIdx.z, co0 = blockIdx.y * 64, P = blockIdx.x * 64;
    const int wid = tid >> 6, l = tid & 63;
    const int wm = wid >> 1, wn = wid & 1;
    const int lr = l & 15, kg = l >> 4;
    f32x4 accE[2][2] = {{{0.f,0.f,0.f,0.f},{0.f,0.f,0.f,0.f}},
                        {{0.f,0.f,0.f,0.f},{0.f,0.f,0.f,0.f}}};
    f32x4 accO[2][2] = {{{0.f,0.f,0.f,0.f},{0.f,0.f,0.f,0.f}},
                        {{0.f,0.f,0.f,0.f},{0.f,0.f,0.f,0.f}}};
    const int nch = Ci >> 5;
    for (int cc = 0; cc < nch; ++cc) {
        __syncthreads();
        for (int i = tid; i < 66 * 4; i += TPB) {
            int r = i >> 2, c4 = i & 3;
            int gr = P - 1 + r;
            uint4 v = make_uint4(0u, 0u, 0u, 0u);
            if (gr >= 0 && gr < Tin)
                v = *(const uint4*)(x + ((size_t)(n * Tin + gr) * Ci + cc * 32 + c4 * 8));
            *(uint4*)&x_lds[r * 40 + c4 * 8] = v;
        }
        for (int i = tid; i < 2 * 64 * 4; i += TPB) {
            int r2 = i >> 2, c4 = i & 3;
            size_t off = (size_t)((r2 >> 6) * Co + co0 + (r2 & 63)) * Ci + cc * 32 + c4 * 8;
            *(uint4*)&we_lds[r2 * 40 + c4 * 8] = *(const uint4*)(wpe + off);
            *(uint4*)&wo_lds[r2 * 40 + c4 * 8] = *(const uint4*)(wpo + off);
        }
        __syncthreads();
        #pragma unroll
        for (int kk = 0; kk < 2; ++kk) {
            bf16x8 aE0 = *(const bf16x8*)&x_lds[(wm * 32 +      lr + kk) * 40 + kg * 8];
            bf16x8 aE1 = *(const bf16x8*)&x_lds[(wm * 32 + 16 + lr + kk) * 40 + kg * 8];
            bf16x8 bE0 = *(const bf16x8*)&we_lds[(kk * 64 + wn * 32 +      lr) * 40 + kg * 8];
            bf16x8 bE1 = *(const bf16x8*)&we_lds[(kk * 64 + wn * 32 + 16 + lr) * 40 + kg * 8];
            accE[0][0] = MFMA(aE0, bE0, accE[0][0]);
            accE[0][1] = MFMA(aE0, bE1, accE[0][1]);
            accE[1][0] = MFMA(aE1, bE0, accE[1][0]);
            accE[1][1] = MFMA(aE1, bE1, accE[1][1]);
            bf16x8 aO0 = *(const bf16x8*)&x_lds[(wm * 32 +      lr + kk + 1) * 40 + kg * 8];
            bf16x8 aO1 = *(const bf16x8*)&x_lds[(wm * 32 + 16 + lr + kk + 1) * 40 + kg * 8];
            bf16x8 bO0 = *(const bf16x8*)&wo_lds[(kk * 64 + wn * 32 +      lr) * 40 + kg * 8];
            bf16x8 bO1 = *(const bf16x8*)&wo_lds[(kk * 64 + wn * 32 + 16 + lr) * 40 + kg * 8];
            accO[0][0] = MFMA(aO0, bO0, accO[0][0]);
            accO[0][1] = MFMA(aO0, bO1, accO[0][1]);
            accO[1][0] = MFMA(aO1, bO0, accO[1][0]);
            accO[1][1] = MFMA(aO1, bO1, accO[1][1]);
        }
    }
    float bb[2] = { bias[co0 + wn * 32 + lr], bias[co0 + wn * 32 + 16 + lr] };
    #pragma unroll
    for (int mf = 0; mf < 2; ++mf)
        #pragma unroll
        for (int nf = 0; nf < 2; ++nf) {
            int co = co0 + wn * 32 + nf * 16 + lr;
            #pragma unroll
            for (int r = 0; r < 4; ++r) {
                int m = wm * 32 + mf * 16 + kg * 4 + r;
                size_t oe = ((size_t)n * (2 * Tin) + (size_t)(P + m) * 2) * Co + co;
                y[oe]      = f2bf(accE[mf][nf][r] + bb[nf]);
                y[oe + Co] = f2bf(accO[mf][nf][r] + bb[nf]);
            }
        }
}

// weight prep: conv [Co][Ci][K] f32 -> [K][Co][Ci] bf16
__global__ __launch_bounds__(TPB) void prep_conv_k(
    const float* __restrict__ w, unsigned short* __restrict__ out, int Co, int Ci, int K)
{
    int id = blockIdx.x * TPB + threadIdx.x;
    if (id >= K * Co * Ci) return;
    int ci = id % Ci, co = (id / Ci) % Co, k = id / (Ci * Co);
    out[id] = f2bf(w[((size_t)co * Ci + ci) * K + k]);
}
// convT [Ci][Co][4] f32 -> even [2][Co][Ci] (w3,w1), odd [2][Co][Ci] (w2,w0)
__global__ __launch_bounds__(TPB) void prep_convt_k(
    const float* __restrict__ w, unsigned short* __restrict__ oute,
    unsigned short* __restrict__ outo, int Co, int Ci)
{
    int id = blockIdx.x * TPB + threadIdx.x;
    if (id >= 2 * Co * Ci) return;
    int ci = id % Ci, co = (id / Ci) % Co, kp = id / (Ci * Co);
    const float* src = w + ((size_t)ci * Co + co) * 4;
    oute[id] = f2bf(src[3 - 2 * kp]);
    outo[id] = f2bf(src[2 - 2 * kp]);
}

// d_out: Co=1, K=7, channel-last bf16 input [16][8192][128] -> f32 [16][8192]
__global__ __launch_bounds__(TPB) void dout_cl_k(
    const unsigned short* __restrict__ x, const float* __restrict__ w,
    const float* __restrict__ b, float* __restrict__ y)
{
    __shared__ unsigned short xs[262 * 40];
    const int tid = threadIdx.x;
    const int tb = blockIdx.x * 256;
    const int n = blockIdx.y;
    float acc = b[0];
    for (int cc = 0; cc < 4; ++cc) {
        __syncthreads();
        for (int i = tid; i < 262 * 4; i += TPB) {
            int r = i >> 2, c4 = i & 3;
            int gr = tb - 3 + r;
            uint4 v = make_uint4(0u, 0u, 0u, 0u);
            if (gr >= 0 && gr < 8192)
                v = *(const uint4*)(x + ((size_t)(n * 8192 + gr) * 128 + cc * 32 + c4 * 8));
            *(uint4*)&xs[r * 40 + c4 * 8] = v;
        }
        __syncthreads();
        #pragma unroll
        for (int k = 0; k < 7; ++k) {
            const unsigned short* row = &xs[(tid + k) * 40];
            #pragma unroll
            for (int e = 0; e < 32; ++e)
                acc = fmaf(bf2f(row[e]), w[(cc * 32 + e) * 7 + k], acc);
        }
    }
    y[(size_t)n * 8192 + tb + tid] = acc;
}

// ---------------- VQ ----------------
#define NVEC 16384
#define KC   4096
#define DD   64
#define NCH  16

__global__ __launch_bounds__(TPB) void vq_norms_k(
    const float* __restrict__ emb1, const float* __restrict__ emb2,
    float* __restrict__ enorm)
{
    int id = blockIdx.x * TPB + threadIdx.x;
    if (id >= 2 * KC) return;
    const float* e = (id < KC) ? (emb1 + (size_t)id * DD) : (emb2 + (size_t)(id - KC) * DD);
    float s = 0.f;
    #pragma unroll
    for (int d = 0; d < DD; ++d) s = fmaf(e[d], e[d], s);
    enorm[id] = s;
}

// 2 z-vectors per thread, resident in explicit f32x4 regs; codebook via scalar
// loads (uniform pointer). Partial-sum lane order identical to prior version.
__global__ __launch_bounds__(TPB, 3) void vq_partial_k(
    const float* __restrict__ z,
    const float* __restrict__ emb1, const float* __restrict__ emb2,
    const float* __restrict__ enorm,
    float* __restrict__ pmin, int* __restrict__ pidx)
{
    const int v0 = blockIdx.x * (TPB * 2) + threadIdx.x;
    const int v1 = v0 + TPB;
    const int ch = blockIdx.y, cb = blockIdx.z;
    const float* emb = cb ? emb2 : emb1;
    const float* en  = enorm + cb * KC;

    f32x4 xa[16], xb[16];
    {
        int b = v0 >> 10, t = v0 & 1023;
        const float* zp = z + ((size_t)b * 128 + cb * 64) * 1024 + t;
        #pragma unroll
        for (int i = 0; i < 16; ++i) {
            xa[i][0] = zp[(size_t)(4 * i + 0) * 1024];
            xa[i][1] = zp[(size_t)(4 * i + 1) * 1024];
            xa[i][2] = zp[(size_t)(4 * i + 2) * 1024];
            xa[i][3] = zp[(size_t)(4 * i + 3) * 1024];
        }
    }
    {
        int b = v1 >> 10, t = v1 & 1023;
        const float* zp = z + ((size_t)b * 128 + cb * 64) * 1024 + t;
        #pragma unroll
        for (int i = 0; i < 16; ++i) {
            xb[i][0] = zp[(size_t)(4 * i + 0) * 1024];
            xb[i][1] = zp[(size_t)(4 * i + 1) * 1024];
            xb[i][2] = zp[(size_t)(4 * i + 2) * 1024];
            xb[i][3] = zp[(size_t)(4 * i + 3) * 1024];
        }
    }

    float best0 = 1e30f, best1 = 1e30f; int bi0 = 0, bi1 = 0;
    const int c0 = ch * (KC / NCH);
    for (int c = c0; c < c0 + KC / NCH; ++c) {
        const f32x4* e4 = (const f32x4*)(emb + (size_t)c * DD);
        f32x4 pa = {0.f, 0.f, 0.f, 0.f}, pb = {0.f, 0.f, 0.f, 0.f};
        #pragma unroll
        for (int i = 0; i < 16; ++i) {
            f32x4 ev = e4[i];
            pa += xa[i] * ev;
            pb += xb[i] * ev;
        }
        float enc = en[c];
        float sa = enc - 2.0f * ((pa[0] + pa[1]) + (pa[2] + pa[3]));
        float sb = enc - 2.0f * ((pb[0] + pb[1]) + (pb[2] + pb[3]));
        if (sa < best0) { best0 = sa; bi0 = c; }
        if (sb < best1) { best1 = sb; bi1 = c; }
    }
    f32x4 na = {0.f,0.f,0.f,0.f}, nb = {0.f,0.f,0.f,0.f};
    #pragma unroll
    for (int i = 0; i < 16; ++i) { na += xa[i] * xa[i]; nb += xb[i] * xb[i]; }
    float xn0 = (na[0] + na[1]) + (na[2] + na[3]);
    float xn1 = (nb[0] + nb[1]) + (nb[2] + nb[3]);
    size_t base = ((size_t)cb * NCH + ch) * NVEC;
    pmin[base + v0] = best0 + xn0;
    pidx[base + v0] = bi0;
    pmin[base + v1] = best1 + xn1;
    pidx[base + v1] = bi1;
}

__global__ __launch_bounds__(TPB) void vq_finalize_k(
    const float* __restrict__ pmin, const int* __restrict__ pidx,
    int* __restrict__ idxf, float* __restrict__ cnt, float* __restrict__ csum)
{
    int gid = blockIdx.x * TPB + threadIdx.x;
    int cb  = gid >> 14;
    int v   = gid & (NVEC - 1);
    float best = pmin[((size_t)cb * NCH + 0) * NVEC + v];
    int   bi   = pidx[((size_t)cb * NCH + 0) * NVEC + v];
    #pragma unroll
    for (int ch = 1; ch < NCH; ++ch) {
        float m  = pmin[((size_t)cb * NCH + ch) * NVEC + v];
        int   ix = pidx[((size_t)cb * NCH + ch) * NVEC + v];
        if (m < best) { best = m; bi = ix; }
    }
    idxf[cb * NVEC + v] = bi;
    atomicAdd(&cnt[cb * KC + bi], 1.0f);
    float s = best;
    #pragma unroll
    for (int off = 32; off; off >>= 1) s += __shfl_down(s, off, 64);
    __shared__ float wsum[4];
    int wid = threadIdx.x >> 6;
    if ((threadIdx.x & 63) == 0) wsum[wid] = s;
    __syncthreads();
    if (threadIdx.x == 0)
        atomicAdd(&csum[cb], wsum[0] + wsum[1] + wsum[2] + wsum[3]);
}

// q -> channel-last bf16 [16][1024][128]
__global__ __launch_bounds__(TPB) void vq_gather_cl_k(
    const int* __restrict__ idxf,
    const float* __restrict__ emb1, const float* __restrict__ emb2,
    unsigned short* __restrict__ q)
{
    int id = blockIdx.x * TPB + threadIdx.x;
    int c = id & 127;
    int t = (id >> 7) & 1023;
    int n = id >> 17;
    int cb = c >> 6, d = c & 63;
    int idx = idxf[cb * NVEC + n * 1024 + t];
    const float* emb = cb ? emb2 : emb1;
    q[id] = f2bf(emb[(size_t)idx * DD + d]);
}

__global__ __launch_bounds__(TPB) void vq_stats_k(
    const float* __restrict__ cnt, const float* __restrict__ csum,
    float* __restrict__ out)
{
    float h0 = 0.f, h1 = 0.f, u0 = 0.f, u1 = 0.f;
    for (int i = threadIdx.x; i < KC; i += TPB) {
        float a0 = cnt[i]      * (1.0f / NVEC);
        float a1 = cnt[KC + i] * (1.0f / NVEC);
        h0 -= a0 * logf(a0 + 1e-10f);
        h1 -= a1 * logf(a1 + 1e-10f);
        u0 += a0 * logf(a0 * (float)KC + 1e-10f);
        u1 += a1 * logf(a1 * (float)KC + 1e-10f);
    }
    #pragma unroll
    for (int off = 32; off; off >>= 1) {
        h0 += __shfl_down(h0, off, 64);
        h1 += __shfl_down(h1, off, 64);
        u0 += __shfl_down(u0, off, 64);
        u1 += __shfl_down(u1, off, 64);
    }
    __shared__ float red[4][4];
    int wid = threadIdx.x >> 6;
    if ((threadIdx.x & 63) == 0) {
        red[wid][0] = h0; red[wid][1] = h1; red[wid][2] = u0; red[wid][3] = u1;
    }
    __syncthreads();
    if (threadIdx.x == 0) {
        h0 = red[0][0] + red[1][0] + red[2][0] + red[3][0];
        h1 = red[0][1] + red[1][1] + red[2][1] + red[3][1];
        u0 = red[0][2] + red[1][2] + red[2][2] + red[3][2];
        u1 = red[0][3] + red[1][3] + red[2][3] + red[3][3];
        out[0] = 0.25f * (csum[0] + csum[1]) * (1.0f / ((float)NVEC * (float)DD));
        out[1] = u0 + u1;
        out[2] = expf(h0);
        out[3] = expf(h1);
    }
}

// ---------------- host helpers ----------------
template<int K, int S, bool RELU, bool RES>
static void launch_conv(hipStream_t st, const float* x, const float* w, const float* b,
                        const float* res, float* y, int Ci, int Ti, int Co, int To)
{
    dim3 g(To / 128, Co / 64, 16);
    conv_tile_k<K, S, RELU, RES><<<g, TPB, 0, st>>>(x, w, b, res, y, Ci, Ti, Co, To);
}

static void resblocks_t(hipStream_t st, float** cur, float** f1, float** f2,
                        const float* w1, const float* b1, const float* w2, const float* b2,
                        int C, int T)
{
    for (int i = 0; i < 2; ++i) {
        launch_conv<3, 1, true, false>(st, *cur, w1 + (size_t)i * C * C * 3, b1 + i * C,
                                       nullptr, *f1, C, T, C, T);
        launch_conv<1, 1, true, true>(st, *f1, w2 + (size_t)i * C * C, b2 + i * C,
                                      *cur, *f2, C, T, C, T);
        float* t = *cur; *cur = *f2; *f2 = t;
    }
}

template<int K, int TOFF, bool RELU, bool RES, int OSTR, int OOFF>
static void gconv(hipStream_t st, const unsigned short* x, const unsigned short* wp,
                  const float* b, const unsigned short* res, unsigned short* y,
                  int Ci, int Tin, int Co, int Tout)
{
    dim3 g(Tin / 64, Co / 64, 16);
    gconv_k<K, TOFF, RELU, RES, OSTR, OOFF><<<g, TPB, 0, st>>>(x, wp, b, res, y,
                                                               Ci, Tin, Co, Tout);
}

static void gconvt2(hipStream_t st, const unsigned short* x, const unsigned short* we,
                    const unsigned short* wo, const float* b, unsigned short* y,
                    int Ci, int Tin, int Co)
{
    dim3 g(Tin / 64, Co / 64, 16);
    gconvt_k<<<g, TPB, 0, st>>>(x, we, wo, b, y, Ci, Tin, Co);
}

static void dresblock(hipStream_t st, unsigned short* cur, unsigned short* o1,
                      unsigned short* o2, const unsigned short* wpc1,
                      const unsigned short* wpc2, const float* b1, const float* b2,
                      int C, int T)
{
    size_t wc1 = (size_t)3 * C * C, wc2 = (size_t)C * C;
    gconv<3, -1, true, false, 1, 0>(st, cur, wpc1, b1, nullptr, o1, C, T, C, T);
    gconv<1,  0, true, true,  1, 0>(st, o1, wpc2, b2, cur, o2, C, T, C, T);
    gconv<3, -1, true, false, 1, 0>(st, o2, wpc1 + wc1, b1 + C, nullptr, o1, C, T, C, T);
    gconv<1,  0, true, true,  1, 0>(st, o1, wpc2 + wc2, b2 + C, o2, cur, C, T, C, T);
}

static void prep_conv(hipStream_t st, const float* w, unsigned short* out,
                      int Co, int Ci, int K)
{
    int n = K * Co * Ci;
    prep_conv_k<<<(n + TPB - 1) / TPB, TPB, 0, st>>>(w, out, Co, Ci, K);
}
static void prep_convt(hipStream_t st, const float* w, unsigned short* oe,
                       unsigned short* oo, int Co, int Ci)
{
    int n = 2 * Co * Ci;
    prep_convt_k<<<(n + TPB - 1) / TPB, TPB, 0, st>>>(w, oe, oo, Co, Ci);
}

extern "C" void kernel_launch(void* const* d_in, const int* in_sizes, int n_in,
                              void* d_out, int out_size, void* d_ws, size_t ws_size,
                              hipStream_t stream)
{
    const float* x       = (const float*)d_in[0];
    const float* e_c1_w  = (const float*)d_in[1];
    const float* e_c1_b  = (const float*)d_in[2];
    const float* e_r1_w1 = (const float*)d_in[3];
    const float* e_r1_b1 = (const float*)d_in[4];
    const float* e_r1_w2 = (const float*)d_in[5];
    const float* e_r1_b2 = (const float*)d_in[6];
    const float* e_c2_w  = (const float*)d_in[7];
    const float* e_c2_b  = (const float*)d_in[8];
    const float* e_r2_w1 = (const float*)d_in[9];
    const float* e_r2_b1 = (const float*)d_in[10];
    const float* e_r2_w2 = (const float*)d_in[11];
    const float* e_r2_b2 = (const float*)d_in[12];
    const float* e_c3_w  = (const float*)d_in[13];
    const float* e_c3_b  = (const float*)d_in[14];
    const float* e_r3_w1 = (const float*)d_in[15];
    const float* e_r3_b1 = (const float*)d_in[16];
    const float* e_r3_w2 = (const float*)d_in[17];
    const float* e_r3_b2 = (const float*)d_in[18];
    const float* e_pr_w  = (const float*)d_in[19];
    const float* e_pr_b  = (const float*)d_in[20];
    const float* emb1    = (const float*)d_in[21];
    const float* emb2    = (const float*)d_in[22];
    const float* d_pr_w  = (const float*)d_in[23];
    const float* d_pr_b  = (const float*)d_in[24];
    const float* d_r1_w1 = (const float*)d_in[25];
    const float* d_r1_b1 = (const float*)d_in[26];
    const float* d_r1_w2 = (const float*)d_in[27];
    const float* d_r1_b2 = (const float*)d_in[28];
    const float* d_u1_w  = (const float*)d_in[29];
    const float* d_u1_b  = (const float*)d_in[30];
    const float* d_r2_w1 = (const float*)d_in[31];
    const float* d_r2_b1 = (const float*)d_in[32];
    const float* d_r2_w2 = (const float*)d_in[33];
    const float* d_r2_b2 = (const float*)d_in[34];
    const float* d_u2_w  = (const float*)d_in[35];
    const float* d_u2_b  = (const float*)d_in[36];
    const float* d_r3_w1 = (const float*)d_in[37];
    const float* d_r3_b1 = (const float*)d_in[38];
    const float* d_r3_w2 = (const float*)d_in[39];
    const float* d_r3_b2 = (const float*)d_in[40];
    const float* d_u3_w  = (const float*)d_in[41];
    const float* d_u3_b  = (const float*)d_in[42];
    const float* d_outw  = (const float*)d_in[43];
    const float* d_outb  = (const float*)d_in[44];

    const size_t BUF = 16777216;
    float* W0   = (float*)d_ws;
    float* W1   = W0 + BUF;
    float* W2   = W1 + BUF;
    float* pmin = W2 + BUF;                    // 2*16*16384 = 524288
    int*   pidx = (int*)(pmin + 524288);       // 524288
    int*   idxf = pidx + 524288;               // 32768
    float* enorm= (float*)(idxf + 32768);      // 8192
    float* cnt  = enorm + 8192;                // 8192
    float* csum = cnt + 8192;                  // 4
    unsigned short* wp = (unsigned short*)(csum + 4);

    unsigned short* wp_dpr  = wp;                      // 1*384*128
    unsigned short* wp_r1c1 = wp_dpr  + 49152;         // 2*3*384*384
    unsigned short* wp_r1c2 = wp_r1c1 + 884736;        // 2*1*384*384
    unsigned short* wp_u1e  = wp_r1c2 + 294912;        // 2*256*384
    unsigned short* wp_u1o  = wp_u1e  + 196608;
    unsigned short* wp_r2c1 = wp_u1o  + 196608;        // 2*3*256*256
    unsigned short* wp_r2c2 = wp_r2c1 + 393216;        // 2*256*256
    unsigned short* wp_u2e  = wp_r2c2 + 131072;        // 2*128*256
    unsigned short* wp_u2o  = wp_u2e  + 65536;
    unsigned short* wp_r3c1 = wp_u2o  + 65536;         // 2*3*128*128
    unsigned short* wp_r3c2 = wp_r3c1 + 98304;         // 2*128*128
    unsigned short* wp_u3e  = wp_r3c2 + 32768;         // 2*128*128
    unsigned short* wp_u3o  = wp_u3e  + 32768;

    unsigned short* bfA = (unsigned short*)W0;
    unsigned short* bfB = bfA + BUF;
    unsigned short* bfC = (unsigned short*)W2;

    float *A = W0, *B = W1, *C = W2, *t_;
    hipStream_t st = stream;

    // ---------------- decoder weight prep ----------------
    prep_conv(st, d_pr_w, wp_dpr, 384, 128, 1);
    prep_conv(st, d_r1_w1,                      wp_r1c1,          384, 384, 3);
    prep_conv(st, d_r1_w1 + (size_t)384*384*3,  wp_r1c1 + 442368, 384, 384, 3);
    prep_conv(st, d_r1_w2,                      wp_r1c2,          384, 384, 1);
    prep_conv(st, d_r1_w2 + (size_t)384*384,    wp_r1c2 + 147456, 384, 384, 1);
    prep_convt(st, d_u1_w, wp_u1e, wp_u1o, 256, 384);
    prep_conv(st, d_r2_w1,                      wp_r2c1,          256, 256, 3);
    prep_conv(st, d_r2_w1 + (size_t)256*256*3,  wp_r2c1 + 196608, 256, 256, 3);
    prep_conv(st, d_r2_w2,                      wp_r2c2,          256, 256, 1);
    prep_conv(st, d_r2_w2 + (size_t)256*256,    wp_r2c2 + 65536,  256, 256, 1);
    prep_convt(st, d_u2_w, wp_u2e, wp_u2o, 128, 256);
    prep_conv(st, d_r3_w1,                      wp_r3c1,          128, 128, 3);
    prep_conv(st, d_r3_w1 + (size_t)128*128*3,  wp_r3c1 + 49152,  128, 128, 3);
    prep_conv(st, d_r3_w2,                      wp_r3c2,          128, 128, 1);
    prep_conv(st, d_r3_w2 + (size_t)128*128,    wp_r3c2 + 16384,  128, 128, 1);
    prep_convt(st, d_u3_w, wp_u3e, wp_u3o, 128, 128);

    // ---------------- encoder (fp32, exact) ----------------
    {
        int total = 16 * 128 * 4096;
        conv1d_k<7, false><<<(total + TPB - 1) / TPB, TPB, 0, st>>>(
            x, e_c1_w, e_c1_b, nullptr, A, 16, 1, 8192, 128, 4096, 2, 3);
    }
    resblocks_t(st, &A, &B, &C, e_r1_w1, e_r1_b1, e_r1_w2, e_r1_b2, 128, 4096);
    launch_conv<5, 2, false, false>(st, A, e_c2_w, e_c2_b, nullptr, B, 128, 4096, 256, 2048);
    t_ = A; A = B; B = t_;
    resblocks_t(st, &A, &B, &C, e_r2_w1, e_r2_b1, e_r2_w2, e_r2_b2, 256, 2048);
    launch_conv<3, 2, false, false>(st, A, e_c3_w, e_c3_b, nullptr, B, 256, 2048, 384, 1024);
    t_ = A; A = B; B = t_;
    resblocks_t(st, &A, &B, &C, e_r3_w1, e_r3_b1, e_r3_w2, e_r3_b2, 384, 1024);
    launch_conv<1, 1, false, false>(st, A, e_pr_w, e_pr_b, nullptr, B, 384, 1024, 128, 1024);
    t_ = A; A = B; B = t_;     // A == z [16,128,1024]

    // ---------------- product VQ (fp32, exact) ----------------
    hipMemsetAsync(cnt, 0, (8192 + 4) * sizeof(float), st);
    vq_norms_k<<<(2 * KC + TPB - 1) / TPB, TPB, 0, st>>>(emb1, emb2, enorm);
    dim3 pg(NVEC / (TPB * 2), NCH, 2);
    vq_partial_k<<<pg, TPB, 0, st>>>(A, emb1, emb2, enorm, pmin, pidx);
    vq_finalize_k<<<2 * NVEC / TPB, TPB, 0, st>>>(pmin, pidx, idxf, cnt, csum);
    vq_gather_cl_k<<<16 * 1024 * 128 / TPB, TPB, 0, st>>>(idxf, emb1, emb2, bfA);

    // ---------------- decoder (bf16 MFMA, channel-last) ----------------
    gconv<1, 0, false, false, 1, 0>(st, bfA, wp_dpr, d_pr_b, nullptr, bfB,
                                    128, 1024, 384, 1024);
    dresblock(st, bfB, bfA, bfC, wp_r1c1, wp_r1c2, d_r1_b1, d_r1_b2, 384, 1024);
    gconvt2(st, bfB, wp_u1e, wp_u1o, d_u1_b, bfA, 384, 1024, 256);
    dresblock(st, bfA, bfB, bfC, wp_r2c1, wp_r2c2, d_r2_b1, d_r2_b2, 256, 2048);
    gconvt2(st, bfA, wp_u2e, wp_u2o, d_u2_b, bfB, 256, 2048, 128);
    dresblock(st, bfB, bfA, bfC, wp_r3c1, wp_r3c2, d_r3_b1, d_r3_b2, 128, 4096);
    gconvt2(st, bfB, wp_u3e, wp_u3o, d_u3_b, bfA, 128, 4096, 128);
    {
        dim3 g(8192 / 256, 16);
        dout_cl_k<<<g, TPB, 0, st>>>(bfA, d_outw, d_outb, (float*)d_out);
    }

    // ---------------- scalar stats ----------------
    vq_stats_k<<<1, TPB, 0, st>>>(cnt, csum, (float*)d_out + 131072);
}